// Round 1
// baseline (523.468 us; speedup 1.0000x reference)
//
#include <hip/hip_runtime.h>
#include <hip/hip_bf16.h>

#define NN 65536
#define EE 1048576
#define BG 64
#define NPGC 1024
#define KKEEP 820

typedef unsigned short u16;
typedef unsigned int u32;
typedef __attribute__((ext_vector_type(4))) float f32x4;
typedef __attribute__((ext_vector_type(8))) short bf16x8;

__device__ __forceinline__ float bfu(u32 u) {
    u32 x = u << 16;
    return __builtin_bit_cast(float, x);
}
__device__ __forceinline__ u16 fbf(float f) {
    __hip_bfloat16 h = __float2bfloat16(f);
    return __builtin_bit_cast(u16, h);
}

// ---------------- CSR build ----------------
__global__ void deg_count_kernel(const int* __restrict__ dst, int* __restrict__ deg, int n) {
    int i = blockIdx.x * 256 + threadIdx.x;
    if (i < n) atomicAdd(&deg[dst[i]], 1);
}

// one block per graph: exclusive scan of 1024 degrees -> node offsets (graph base = g*16384)
__global__ __launch_bounds__(256) void csr_offsets_kernel(const int* __restrict__ deg,
                                                          int* __restrict__ noff,
                                                          int* __restrict__ cur) {
    __shared__ int part[256];
    int g = blockIdx.x, t = threadIdx.x;
    int base = g * NPGC;
    int v0 = deg[base + t * 4 + 0];
    int v1 = deg[base + t * 4 + 1];
    int v2 = deg[base + t * 4 + 2];
    int v3 = deg[base + t * 4 + 3];
    int tot = v0 + v1 + v2 + v3;
    part[t] = tot;
    __syncthreads();
    for (int d = 1; d < 256; d <<= 1) {
        int add = (t >= d) ? part[t - d] : 0;
        __syncthreads();
        part[t] += add;
        __syncthreads();
    }
    int excl = (t == 0) ? 0 : part[t - 1];
    int o = g * (NPGC * 16) + excl;
    int i0 = base + t * 4;
    noff[i0 + 0] = o;            cur[i0 + 0] = o;
    noff[i0 + 1] = o + v0;       cur[i0 + 1] = o + v0;
    noff[i0 + 2] = o + v0 + v1;  cur[i0 + 2] = o + v0 + v1;
    noff[i0 + 3] = o + v0 + v1 + v2; cur[i0 + 3] = o + v0 + v1 + v2;
}

__global__ void csr_fill_kernel(const int* __restrict__ src, const int* __restrict__ dst,
                                int* __restrict__ cur, int* __restrict__ csr, int n) {
    int i = blockIdx.x * 256 + threadIdx.x;
    if (i < n) {
        int p = atomicAdd(&cur[dst[i]], 1);
        csr[p] = src[i];
    }
}

// ---------------- casts ----------------
// in: fp32 [NN][128]; gate: per-node scalar (may be null); out: bf16
__global__ void cast_gate_kernel(const float* __restrict__ in, const float* __restrict__ gate,
                                 u16* __restrict__ out, int n4) {
    int i = blockIdx.x * 256 + threadIdx.x;
    if (i >= n4) return;
    float4 v = reinterpret_cast<const float4*>(in)[i];
    float g = gate ? gate[i >> 5] : 1.0f;  // 32 float4 per node (128 feats)
    u32 lo = (u32)fbf(v.x * g) | ((u32)fbf(v.y * g) << 16);
    u32 hi = (u32)fbf(v.z * g) | ((u32)fbf(v.w * g) << 16);
    uint2 o = {lo, hi};
    reinterpret_cast<uint2*>(out)[i] = o;
}

// WT[col][k] = (col<128 ? Wrel[k][col] : Wroot[k][col-128]) as bf16, 256x128
__global__ void prep_w_kernel(const float* __restrict__ Wrel, const float* __restrict__ Wroot,
                              u16* __restrict__ WT) {
    int idx = blockIdx.x * 256 + threadIdx.x;  // 32768
    int col = idx >> 7, k = idx & 127;
    float v = (col < 128) ? Wrel[k * 128 + col] : Wroot[k * 128 + (col - 128)];
    WT[idx] = fbf(v);
}

// ---------------- GEMM: Y[N][256] = X[N][128] @ Wcat[128][256]  (bf16 in/out, fp32 acc)
__global__ __launch_bounds__(256, 2) void gemm_kernel(const u16* __restrict__ X,
                                                      const u16* __restrict__ WT,
                                                      u16* __restrict__ Y) {
    __shared__ u16 As[128][72];  // pitch 72 u16 = 144B (16B aligned, 2-way bank alias = free)
    __shared__ u16 Bs[128][72];
    int rb = blockIdx.x * 128;
    int cb = blockIdx.y * 128;
    int tid = threadIdx.x;
    int lane = tid & 63, wid = tid >> 6;
    int wr = (wid >> 1) << 6, wc = (wid & 1) << 6;
    int lr = lane & 15, lk = (lane >> 4) << 3;
    f32x4 acc[4][4] = {};

    for (int half = 0; half < 2; ++half) {
        int k0 = half << 6;
        if (half) __syncthreads();
        for (int i = tid; i < 1024; i += 256) {
            int r = i >> 3, c = (i & 7) << 3;
            *reinterpret_cast<uint4*>(&As[r][c]) =
                *reinterpret_cast<const uint4*>(X + (rb + r) * 128 + k0 + c);
            *reinterpret_cast<uint4*>(&Bs[r][c]) =
                *reinterpret_cast<const uint4*>(WT + (cb + r) * 128 + k0 + c);
        }
        __syncthreads();
        for (int kk = 0; kk < 64; kk += 32) {
            bf16x8 a[4], b[4];
            for (int m = 0; m < 4; ++m)
                a[m] = *reinterpret_cast<const bf16x8*>(&As[wr + m * 16 + lr][kk + lk]);
            for (int n = 0; n < 4; ++n)
                b[n] = *reinterpret_cast<const bf16x8*>(&Bs[wc + n * 16 + lr][kk + lk]);
            for (int m = 0; m < 4; ++m)
                for (int n = 0; n < 4; ++n)
                    acc[m][n] = __builtin_amdgcn_mfma_f32_16x16x32_bf16(a[m], b[n], acc[m][n], 0, 0, 0);
        }
    }
    int orow0 = rb + wr + ((lane >> 4) << 2);
    int ocol0 = cb + wc + (lane & 15);
    for (int m = 0; m < 4; ++m)
        for (int n = 0; n < 4; ++n)
            for (int r = 0; r < 4; ++r)
                Y[(size_t)(orow0 + m * 16 + r) * 256 + ocol0 + n * 16] = fbf(acc[m][n][r]);
}

// ---------------- aggregate + combine + relu ----------------
// out[i] = relu( keep_i * (sum_{s in N(i)} Yrel[s]) / max(cnt,1) + bias + Yroot[i] )
// Y: bf16 [NN][256] (cols 0..127 = Xrel, 128..255 = Xroot). keep==null -> unmasked.
__global__ __launch_bounds__(256) void agg_kernel(const u16* __restrict__ Y,
                                                  const int* __restrict__ csr,
                                                  const int* __restrict__ noff,
                                                  const int* __restrict__ deg,
                                                  const float* __restrict__ bias,
                                                  const float* __restrict__ keep,
                                                  float* __restrict__ outf,
                                                  u16* __restrict__ outb) {
    int node = blockIdx.x * 4 + (threadIdx.x >> 6);
    int lane = threadIdx.x & 63;
    int off = noff[node], dg = deg[node];
    float a0 = 0.f, a1 = 0.f, cnt = 0.f;
    for (int e = 0; e < dg; ++e) {
        int s = csr[off + e];
        cnt += keep ? keep[s] : 1.0f;
        u32 v = *reinterpret_cast<const u32*>(Y + (size_t)s * 256 + lane * 2);
        a0 += bfu(v & 0xffffu);
        a1 += bfu(v >> 16);
    }
    float ki = keep ? keep[node] : 1.0f;
    float inv = ki / fmaxf(cnt, 1.0f);
    u32 vr = *reinterpret_cast<const u32*>(Y + (size_t)node * 256 + 128 + lane * 2);
    float r0 = fmaxf(a0 * inv + bias[lane * 2] + bfu(vr & 0xffffu), 0.f);
    float r1 = fmaxf(a1 * inv + bias[lane * 2 + 1] + bfu(vr >> 16), 0.f);
    float2 o = {r0, r1};
    *reinterpret_cast<float2*>(outf + (size_t)node * 128 + lane * 2) = o;
    if (outb) {
        u32 p = ((u32)fbf(r1) << 16) | (u32)fbf(r0);
        *reinterpret_cast<u32*>(outb + (size_t)node * 128 + lane * 2) = p;
    }
}

// ---------------- pooling: xs[g][base..base+127] += sum over 128-node chunk / denom
__global__ __launch_bounds__(128) void pool_kernel(const float* __restrict__ X,
                                                   const float* __restrict__ keep,
                                                   float* __restrict__ xs, int base, float denom) {
    int g = blockIdx.x >> 3, c = blockIdx.x & 7, f = threadIdx.x;
    int n0 = g * NPGC + c * 128;
    float s = 0.f;
    for (int n = 0; n < 128; ++n) {
        float w = keep ? keep[n0 + n] : 1.0f;
        s += X[(size_t)(n0 + n) * 128 + f] * w;
    }
    atomicAdd(&xs[g * 384 + base + f], s / denom);
}

// ---------------- score dots: srel[i]=x2[i].Wsrel, sroot[i]=x2[i].Wsroot
__global__ __launch_bounds__(256) void score_dot_kernel(const float* __restrict__ X2,
                                                        const float* __restrict__ wrel,
                                                        const float* __restrict__ wroot,
                                                        float* __restrict__ srel,
                                                        float* __restrict__ sroot) {
    int node = blockIdx.x * 4 + (threadIdx.x >> 6);
    int lane = threadIdx.x & 63;
    float x0 = X2[(size_t)node * 128 + lane];
    float x1 = X2[(size_t)node * 128 + 64 + lane];
    float pr = x0 * wrel[lane] + x1 * wrel[64 + lane];
    float po = x0 * wroot[lane] + x1 * wroot[64 + lane];
    for (int d = 32; d >= 1; d >>= 1) {
        pr += __shfl_down(pr, d, 64);
        po += __shfl_down(po, d, 64);
    }
    if (lane == 0) { srel[node] = pr; sroot[node] = po; }
}

__global__ void score_agg_kernel(const float* __restrict__ srel, const float* __restrict__ sroot,
                                 const float* __restrict__ bs, const int* __restrict__ csr,
                                 const int* __restrict__ noff, const int* __restrict__ deg,
                                 float* __restrict__ score) {
    int i = blockIdx.x * 256 + threadIdx.x;
    if (i >= NN) return;
    int off = noff[i], dg = deg[i];
    float s = 0.f;
    for (int e = 0; e < dg; ++e) s += srel[csr[off + e]];
    score[i] = s / fmaxf((float)dg, 1.0f) + bs[0] + sroot[i];
}

// ---------------- per-graph top-K via bitonic sort (desc score, asc idx tiebreak)
__global__ __launch_bounds__(256) void topk_kernel(const float* __restrict__ score,
                                                   float* __restrict__ keep,
                                                   float* __restrict__ gate) {
    __shared__ float sc[NPGC];
    __shared__ int si[NPGC];
    int g = blockIdx.x, t = threadIdx.x;
    for (int i = t; i < NPGC; i += 256) { sc[i] = score[g * NPGC + i]; si[i] = i; }
    __syncthreads();
    for (int k = 2; k <= NPGC; k <<= 1) {
        for (int j = k >> 1; j > 0; j >>= 1) {
            for (int i = t; i < NPGC; i += 256) {
                int ixj = i ^ j;
                if (ixj > i) {
                    float a = sc[i], b = sc[ixj];
                    int ai = si[i], bi = si[ixj];
                    bool less = (a > b) || (a == b && ai < bi);  // "a precedes b"
                    bool up = ((i & k) == 0);
                    if (less != up) { sc[i] = b; sc[ixj] = a; si[i] = bi; si[ixj] = ai; }
                }
            }
            __syncthreads();
        }
    }
    for (int i = t; i < NPGC; i += 256) {
        int node = g * NPGC + si[i];
        float kf = (i < KKEEP) ? 1.f : 0.f;
        keep[node] = kf;
        gate[node] = kf * tanhf(sc[i]);
    }
}

// ---------------- MLP head + log_softmax (one block per graph)
__global__ __launch_bounds__(128) void mlp_kernel(const float* __restrict__ xs,
                                                  const float* __restrict__ Wl1,
                                                  const float* __restrict__ bl1,
                                                  const float* __restrict__ Wl2,
                                                  const float* __restrict__ bl2,
                                                  float* __restrict__ out) {
    __shared__ float xsl[384];
    __shared__ float hl[128];
    __shared__ float lg[10];
    int g = blockIdx.x, t = threadIdx.x;
    for (int i = t; i < 384; i += 128) xsl[i] = xs[g * 384 + i];
    __syncthreads();
    float h = bl1[t];
    for (int k = 0; k < 384; ++k) h += xsl[k] * Wl1[k * 128 + t];
    hl[t] = fmaxf(h, 0.f);
    __syncthreads();
    if (t < 10) {
        float l = bl2[t];
        for (int k = 0; k < 128; ++k) l += hl[k] * Wl2[k * 10 + t];
        lg[t] = l;
    }
    __syncthreads();
    if (t < 10) {
        float m = lg[0];
        for (int c = 1; c < 10; ++c) m = fmaxf(m, lg[c]);
        float s = 0.f;
        for (int c = 0; c < 10; ++c) s += expf(lg[c] - m);
        out[g * 10 + t] = lg[t] - m - logf(s);
    }
}

extern "C" void kernel_launch(void* const* d_in, const int* in_sizes, int n_in,
                              void* d_out, int out_size, void* d_ws, size_t ws_size,
                              hipStream_t stream) {
    const float* x       = (const float*)d_in[0];
    const int*   src     = (const int*)d_in[1];
    const int*   dst     = (const int*)d_in[2];
    const float* W1_rel  = (const float*)d_in[3];
    const float* b1      = (const float*)d_in[4];
    const float* W1_root = (const float*)d_in[5];
    const float* W2_rel  = (const float*)d_in[6];
    const float* b2      = (const float*)d_in[7];
    const float* W2_root = (const float*)d_in[8];
    const float* W3_rel  = (const float*)d_in[9];
    const float* b3      = (const float*)d_in[10];
    const float* W3_root = (const float*)d_in[11];
    const float* Ws_rel  = (const float*)d_in[12];
    const float* bs      = (const float*)d_in[13];
    const float* Ws_root = (const float*)d_in[14];
    const float* Wl1     = (const float*)d_in[15];
    const float* bl1     = (const float*)d_in[16];
    const float* Wl2     = (const float*)d_in[17];
    const float* bl2     = (const float*)d_in[18];

    char* ws = (char*)d_ws;
    size_t off = 0;
    auto alloc = [&](size_t bytes) -> void* {
        void* p = ws + off;
        off += (bytes + 255) & ~(size_t)255;
        return p;
    };
    u16*   XB    = (u16*)alloc((size_t)NN * 128 * 2);
    u16*   YB    = (u16*)alloc((size_t)NN * 256 * 2);
    float* X1    = (float*)alloc((size_t)NN * 128 * 4);  // x1, reused for x3
    float* X2    = (float*)alloc((size_t)NN * 128 * 4);
    u16*   WT    = (u16*)alloc(256 * 128 * 2);
    float* SREL  = (float*)alloc(NN * 4);
    float* SROOT = (float*)alloc(NN * 4);
    float* SCORE = (float*)alloc(NN * 4);
    float* GATE  = (float*)alloc(NN * 4);
    float* KEEP  = (float*)alloc(NN * 4);
    int*   DEG   = (int*)alloc(NN * 4);
    int*   NOFF  = (int*)alloc(NN * 4);
    int*   CUR   = (int*)alloc(NN * 4);
    int*   CSR   = (int*)alloc((size_t)EE * 4);
    float* XS    = (float*)alloc(BG * 384 * 4);
    (void)ws_size; (void)n_in; (void)in_sizes; (void)out_size;

    hipMemsetAsync(DEG, 0, NN * 4, stream);
    hipMemsetAsync(XS, 0, BG * 384 * 4, stream);

    // CSR build (by dst)
    deg_count_kernel<<<EE / 256, 256, 0, stream>>>(dst, DEG, EE);
    csr_offsets_kernel<<<BG, 256, 0, stream>>>(DEG, NOFF, CUR);
    csr_fill_kernel<<<EE / 256, 256, 0, stream>>>(src, dst, CUR, CSR, EE);

    // cast input to bf16
    cast_gate_kernel<<<(NN * 128 / 4) / 256, 256, 0, stream>>>(x, nullptr, XB, NN * 128 / 4);

    // ---- conv1 ----
    prep_w_kernel<<<128, 256, 0, stream>>>(W1_rel, W1_root, WT);
    gemm_kernel<<<dim3(NN / 128, 2), 256, 0, stream>>>(XB, WT, YB);
    agg_kernel<<<NN / 4, 256, 0, stream>>>(YB, CSR, NOFF, DEG, b1, nullptr, X1, XB);
    pool_kernel<<<BG * 8, 128, 0, stream>>>(X1, nullptr, XS, 0, 1024.f);

    // ---- conv2 ----
    prep_w_kernel<<<128, 256, 0, stream>>>(W2_rel, W2_root, WT);
    gemm_kernel<<<dim3(NN / 128, 2), 256, 0, stream>>>(XB, WT, YB);
    agg_kernel<<<NN / 4, 256, 0, stream>>>(YB, CSR, NOFF, DEG, b2, nullptr, X2, XB);
    pool_kernel<<<BG * 8, 128, 0, stream>>>(X2, nullptr, XS, 128, 1024.f);

    // ---- SAGPooling score ----
    score_dot_kernel<<<NN / 4, 256, 0, stream>>>(X2, Ws_rel, Ws_root, SREL, SROOT);
    score_agg_kernel<<<NN / 256, 256, 0, stream>>>(SREL, SROOT, bs, CSR, NOFF, DEG, SCORE);
    topk_kernel<<<BG, 256, 0, stream>>>(SCORE, KEEP, GATE);
    cast_gate_kernel<<<(NN * 128 / 4) / 256, 256, 0, stream>>>(X2, GATE, XB, NN * 128 / 4);

    // ---- conv3 (masked) ----
    prep_w_kernel<<<128, 256, 0, stream>>>(W3_rel, W3_root, WT);
    gemm_kernel<<<dim3(NN / 128, 2), 256, 0, stream>>>(XB, WT, YB);
    agg_kernel<<<NN / 4, 256, 0, stream>>>(YB, CSR, NOFF, DEG, b3, KEEP, X1, nullptr);
    pool_kernel<<<BG * 8, 128, 0, stream>>>(X1, KEEP, XS, 256, (float)KKEEP);

    // ---- MLP head ----
    mlp_kernel<<<BG, 128, 0, stream>>>(XS, Wl1, bl1, Wl2, bl2, (float*)d_out);
}

// Round 2
// 356.368 us; speedup vs baseline: 1.4689x; 1.4689x over previous
//
#include <hip/hip_runtime.h>
#include <hip/hip_bf16.h>

#define NN 65536
#define EE 1048576
#define BG 64
#define NPGC 1024
#define KKEEP 820

typedef unsigned short u16;
typedef unsigned int u32;
typedef __attribute__((ext_vector_type(4))) float f32x4;
typedef __attribute__((ext_vector_type(8))) short bf16x8;

__device__ __forceinline__ float bfu(u32 u) {
    u32 x = u << 16;
    return __builtin_bit_cast(float, x);
}
__device__ __forceinline__ u16 fbf(float f) {
    __hip_bfloat16 h = __float2bfloat16(f);
    return __builtin_bit_cast(u16, h);
}

// ---------------- CSR build ----------------
__global__ void deg_count_kernel(const int* __restrict__ dst, int* __restrict__ deg, int n) {
    int i = blockIdx.x * 256 + threadIdx.x;
    if (i < n) atomicAdd(&deg[dst[i]], 1);
}

// one block per graph: exclusive scan of 1024 degrees -> node offsets (graph base = g*16384)
__global__ __launch_bounds__(256) void csr_offsets_kernel(const int* __restrict__ deg,
                                                          int* __restrict__ noff,
                                                          int* __restrict__ cur) {
    __shared__ int part[256];
    int g = blockIdx.x, t = threadIdx.x;
    int base = g * NPGC;
    int v0 = deg[base + t * 4 + 0];
    int v1 = deg[base + t * 4 + 1];
    int v2 = deg[base + t * 4 + 2];
    int v3 = deg[base + t * 4 + 3];
    int tot = v0 + v1 + v2 + v3;
    part[t] = tot;
    __syncthreads();
    for (int d = 1; d < 256; d <<= 1) {
        int add = (t >= d) ? part[t - d] : 0;
        __syncthreads();
        part[t] += add;
        __syncthreads();
    }
    int excl = (t == 0) ? 0 : part[t - 1];
    int o = g * (NPGC * 16) + excl;
    int i0 = base + t * 4;
    noff[i0 + 0] = o;            cur[i0 + 0] = o;
    noff[i0 + 1] = o + v0;       cur[i0 + 1] = o + v0;
    noff[i0 + 2] = o + v0 + v1;  cur[i0 + 2] = o + v0 + v1;
    noff[i0 + 3] = o + v0 + v1 + v2; cur[i0 + 3] = o + v0 + v1 + v2;
}

__global__ void csr_fill_kernel(const int* __restrict__ src, const int* __restrict__ dst,
                                int* __restrict__ cur, int* __restrict__ csr, int n) {
    int i = blockIdx.x * 256 + threadIdx.x;
    if (i < n) {
        int p = atomicAdd(&cur[dst[i]], 1);
        csr[p] = src[i];
    }
}

// ---------------- casts ----------------
// fp32 -> bf16 (initial input cast)
__global__ void cast_kernel(const float* __restrict__ in, u16* __restrict__ out, int n4) {
    int i = blockIdx.x * 256 + threadIdx.x;
    if (i >= n4) return;
    float4 v = reinterpret_cast<const float4*>(in)[i];
    u32 lo = (u32)fbf(v.x) | ((u32)fbf(v.y) << 16);
    u32 hi = (u32)fbf(v.z) | ((u32)fbf(v.w) << 16);
    uint2 o = {lo, hi};
    reinterpret_cast<uint2*>(out)[i] = o;
}

// bf16 features * per-node gate -> bf16
__global__ void gate_bf16_kernel(const u16* __restrict__ in, const float* __restrict__ gate,
                                 u16* __restrict__ out, int n4) {
    int i = blockIdx.x * 256 + threadIdx.x;
    if (i >= n4) return;
    uint2 v = reinterpret_cast<const uint2*>(in)[i];  // 4 bf16
    float g = gate[i >> 5];                           // 32 uint2 per node (128 feats)
    u32 lo = (u32)fbf(bfu(v.x & 0xffffu) * g) | ((u32)fbf(bfu(v.x >> 16) * g) << 16);
    u32 hi = (u32)fbf(bfu(v.y & 0xffffu) * g) | ((u32)fbf(bfu(v.y >> 16) * g) << 16);
    uint2 o = {lo, hi};
    reinterpret_cast<uint2*>(out)[i] = o;
}

// WT[col][k] = (col<128 ? Wrel[k][col] : Wroot[k][col-128]) as bf16, 256x128
__global__ void prep_w_kernel(const float* __restrict__ Wrel, const float* __restrict__ Wroot,
                              u16* __restrict__ WT) {
    int idx = blockIdx.x * 256 + threadIdx.x;  // 32768
    int col = idx >> 7, k = idx & 127;
    float v = (col < 128) ? Wrel[k * 128 + col] : Wroot[k * 128 + (col - 128)];
    WT[idx] = fbf(v);
}

// ---------------- GEMM: Y[N][256] = X[N][128] @ Wcat[128][256]  (bf16 in/out, fp32 acc)
__global__ __launch_bounds__(256, 2) void gemm_kernel(const u16* __restrict__ X,
                                                      const u16* __restrict__ WT,
                                                      u16* __restrict__ Y) {
    __shared__ u16 As[128][72];  // pitch 72 u16 = 144B (2-way bank alias = free)
    __shared__ u16 Bs[128][72];
    int rb = blockIdx.x * 128;
    int cb = blockIdx.y * 128;
    int tid = threadIdx.x;
    int lane = tid & 63, wid = tid >> 6;
    int wr = (wid >> 1) << 6, wc = (wid & 1) << 6;
    int lr = lane & 15, lk = (lane >> 4) << 3;
    f32x4 acc[4][4] = {};

    for (int half = 0; half < 2; ++half) {
        int k0 = half << 6;
        if (half) __syncthreads();
        for (int i = tid; i < 1024; i += 256) {
            int r = i >> 3, c = (i & 7) << 3;
            *reinterpret_cast<uint4*>(&As[r][c]) =
                *reinterpret_cast<const uint4*>(X + (rb + r) * 128 + k0 + c);
            *reinterpret_cast<uint4*>(&Bs[r][c]) =
                *reinterpret_cast<const uint4*>(WT + (cb + r) * 128 + k0 + c);
        }
        __syncthreads();
        for (int kk = 0; kk < 64; kk += 32) {
            bf16x8 a[4], b[4];
            for (int m = 0; m < 4; ++m)
                a[m] = *reinterpret_cast<const bf16x8*>(&As[wr + m * 16 + lr][kk + lk]);
            for (int n = 0; n < 4; ++n)
                b[n] = *reinterpret_cast<const bf16x8*>(&Bs[wc + n * 16 + lr][kk + lk]);
            for (int m = 0; m < 4; ++m)
                for (int n = 0; n < 4; ++n)
                    acc[m][n] = __builtin_amdgcn_mfma_f32_16x16x32_bf16(a[m], b[n], acc[m][n], 0, 0, 0);
        }
    }
    int orow0 = rb + wr + ((lane >> 4) << 2);
    int ocol0 = cb + wc + (lane & 15);
    for (int m = 0; m < 4; ++m)
        for (int n = 0; n < 4; ++n)
            for (int r = 0; r < 4; ++r)
                Y[(size_t)(orow0 + m * 16 + r) * 256 + ocol0 + n * 16] = fbf(acc[m][n][r]);
}

// ---------------- fused aggregate + combine + relu + pool (+score) ----------------
// r[i] = relu( ki * (sum_{s in N(i)} Yrel[s]) / max(cnt,1) + bias + Yroot[i] )
// outb (if non-null): bf16 features for next layer
// srel/sroot (if non-null): SAGPool score partial dots of r
// pool: xs[g][base..base+127] += poolw * r / denom  (poolw = keep for conv3 else 1)
__global__ __launch_bounds__(256) void agg_kernel(const u16* __restrict__ Y,
                                                  const int* __restrict__ csr,
                                                  const int* __restrict__ noff,
                                                  const int* __restrict__ deg,
                                                  const float* __restrict__ bias,
                                                  const float* __restrict__ keep,
                                                  u16* __restrict__ outb,
                                                  const float* __restrict__ wsrel,
                                                  const float* __restrict__ wsroot,
                                                  float* __restrict__ srel,
                                                  float* __restrict__ sroot,
                                                  float* __restrict__ xs,
                                                  int base, float invdenom) {
    __shared__ float pool[4][128];
    int wid = threadIdx.x >> 6, lane = threadIdx.x & 63;
    int node = blockIdx.x * 4 + wid;
    int off = noff[node], dg = deg[node];

    // issue root-part + bias loads early
    u32 vr = *reinterpret_cast<const u32*>(Y + (size_t)node * 256 + 128 + lane * 2);
    float2 bb = reinterpret_cast<const float2*>(bias)[lane];

    // lane-parallel neighbor index load (covers dg<=64; tail loop below for overflow)
    int sid = (lane < dg) ? csr[off + lane] : 0;
    float cnt;
    if (keep) {
        float kw = (lane < dg) ? keep[sid] : 0.f;
        for (int d = 1; d < 64; d <<= 1) kw += __shfl_xor(kw, d, 64);
        cnt = kw;
    } else {
        cnt = (float)dg;
    }

    int dgc = dg < 64 ? dg : 64;
    float a0 = 0.f, a1 = 0.f;
    int e = 0;
    for (; e + 4 <= dgc; e += 4) {
        int s0 = __builtin_amdgcn_readlane(sid, e);
        int s1 = __builtin_amdgcn_readlane(sid, e + 1);
        int s2 = __builtin_amdgcn_readlane(sid, e + 2);
        int s3 = __builtin_amdgcn_readlane(sid, e + 3);
        u32 v0 = *reinterpret_cast<const u32*>(Y + (size_t)s0 * 256 + lane * 2);
        u32 v1 = *reinterpret_cast<const u32*>(Y + (size_t)s1 * 256 + lane * 2);
        u32 v2 = *reinterpret_cast<const u32*>(Y + (size_t)s2 * 256 + lane * 2);
        u32 v3 = *reinterpret_cast<const u32*>(Y + (size_t)s3 * 256 + lane * 2);
        a0 += bfu(v0 & 0xffffu) + bfu(v1 & 0xffffu) + bfu(v2 & 0xffffu) + bfu(v3 & 0xffffu);
        a1 += bfu(v0 >> 16) + bfu(v1 >> 16) + bfu(v2 >> 16) + bfu(v3 >> 16);
    }
    for (; e < dgc; ++e) {
        int s = __builtin_amdgcn_readlane(sid, e);
        u32 v = *reinterpret_cast<const u32*>(Y + (size_t)s * 256 + lane * 2);
        a0 += bfu(v & 0xffffu);
        a1 += bfu(v >> 16);
    }
    for (; e < dg; ++e) {  // rare: degree > 64
        int s = csr[off + e];
        if (keep) cnt += keep[s] * (1.f / 64.f) * 0.f + (lane == 0 ? 0.f : 0.f), cnt += 0.f;
        if (keep) { float kk = keep[s]; cnt += kk - kk; cnt += kk; }  // uniform add
        u32 v = *reinterpret_cast<const u32*>(Y + (size_t)s * 256 + lane * 2);
        a0 += bfu(v & 0xffffu);
        a1 += bfu(v >> 16);
    }

    float ki = keep ? keep[node] : 1.0f;
    float inv = ki / fmaxf(cnt, 1.0f);
    float r0 = fmaxf(a0 * inv + bb.x + bfu(vr & 0xffffu), 0.f);
    float r1 = fmaxf(a1 * inv + bb.y + bfu(vr >> 16), 0.f);

    if (outb) {
        u32 p = ((u32)fbf(r1) << 16) | (u32)fbf(r0);
        *reinterpret_cast<u32*>(outb + (size_t)node * 128 + lane * 2) = p;
    }

    if (srel) {  // SAGPool score partial dots (conv2 only)
        float2 w0 = reinterpret_cast<const float2*>(wsrel)[lane];
        float2 w1 = reinterpret_cast<const float2*>(wsroot)[lane];
        float pr = r0 * w0.x + r1 * w0.y;
        float po = r0 * w1.x + r1 * w1.y;
        for (int d = 1; d < 64; d <<= 1) {
            pr += __shfl_xor(pr, d, 64);
            po += __shfl_xor(po, d, 64);
        }
        if (lane == 0) { srel[node] = pr; sroot[node] = po; }
    }

    // pool: LDS partial across the block's 4 nodes, then one atomic per feature
    float pw = keep ? ki : 1.0f;
    pool[wid][lane * 2] = r0 * pw;
    pool[wid][lane * 2 + 1] = r1 * pw;
    __syncthreads();
    int t = threadIdx.x;
    if (t < 128) {
        float s = pool[0][t] + pool[1][t] + pool[2][t] + pool[3][t];
        int g = blockIdx.x >> 8;  // 256 blocks per graph
        atomicAdd(&xs[g * 384 + base + t], s * invdenom);
    }
}

__global__ void score_agg_kernel(const float* __restrict__ srel, const float* __restrict__ sroot,
                                 const float* __restrict__ bs, const int* __restrict__ csr,
                                 const int* __restrict__ noff, const int* __restrict__ deg,
                                 float* __restrict__ score) {
    int i = blockIdx.x * 256 + threadIdx.x;
    if (i >= NN) return;
    int off = noff[i], dg = deg[i];
    float s = 0.f;
    for (int e = 0; e < dg; ++e) s += srel[csr[off + e]];
    score[i] = s / fmaxf((float)dg, 1.0f) + bs[0] + sroot[i];
}

// ---------------- per-graph top-K via bitonic sort (desc score, asc idx tiebreak)
__global__ __launch_bounds__(1024) void topk_kernel(const float* __restrict__ score,
                                                    float* __restrict__ keep,
                                                    float* __restrict__ gate) {
    __shared__ float sc[NPGC];
    __shared__ int si[NPGC];
    int g = blockIdx.x, t = threadIdx.x;
    sc[t] = score[g * NPGC + t];
    si[t] = t;
    __syncthreads();
    for (int k = 2; k <= NPGC; k <<= 1) {
        for (int j = k >> 1; j > 0; j >>= 1) {
            int ixj = t ^ j;
            if (ixj > t) {
                float a = sc[t], b = sc[ixj];
                int ai = si[t], bi = si[ixj];
                bool less = (a > b) || (a == b && ai < bi);  // "a precedes b" in desc order
                bool up = ((t & k) == 0);
                if (less != up) { sc[t] = b; sc[ixj] = a; si[t] = bi; si[ixj] = ai; }
            }
            __syncthreads();
        }
    }
    int node = g * NPGC + si[t];
    float kf = (t < KKEEP) ? 1.f : 0.f;
    keep[node] = kf;
    gate[node] = kf * tanhf(sc[t]);
}

// ---------------- MLP head + log_softmax (one block per graph)
__global__ __launch_bounds__(128) void mlp_kernel(const float* __restrict__ xs,
                                                  const float* __restrict__ Wl1,
                                                  const float* __restrict__ bl1,
                                                  const float* __restrict__ Wl2,
                                                  const float* __restrict__ bl2,
                                                  float* __restrict__ out) {
    __shared__ float xsl[384];
    __shared__ float hl[128];
    __shared__ float lg[10];
    int g = blockIdx.x, t = threadIdx.x;
    for (int i = t; i < 384; i += 128) xsl[i] = xs[g * 384 + i];
    __syncthreads();
    float h = bl1[t];
    for (int k = 0; k < 384; ++k) h += xsl[k] * Wl1[k * 128 + t];
    hl[t] = fmaxf(h, 0.f);
    __syncthreads();
    if (t < 10) {
        float l = bl2[t];
        for (int k = 0; k < 128; ++k) l += hl[k] * Wl2[k * 10 + t];
        lg[t] = l;
    }
    __syncthreads();
    if (t < 10) {
        float m = lg[0];
        for (int c = 1; c < 10; ++c) m = fmaxf(m, lg[c]);
        float s = 0.f;
        for (int c = 0; c < 10; ++c) s += expf(lg[c] - m);
        out[g * 10 + t] = lg[t] - m - logf(s);
    }
}

extern "C" void kernel_launch(void* const* d_in, const int* in_sizes, int n_in,
                              void* d_out, int out_size, void* d_ws, size_t ws_size,
                              hipStream_t stream) {
    const float* x       = (const float*)d_in[0];
    const int*   src     = (const int*)d_in[1];
    const int*   dst     = (const int*)d_in[2];
    const float* W1_rel  = (const float*)d_in[3];
    const float* b1      = (const float*)d_in[4];
    const float* W1_root = (const float*)d_in[5];
    const float* W2_rel  = (const float*)d_in[6];
    const float* b2      = (const float*)d_in[7];
    const float* W2_root = (const float*)d_in[8];
    const float* W3_rel  = (const float*)d_in[9];
    const float* b3      = (const float*)d_in[10];
    const float* W3_root = (const float*)d_in[11];
    const float* Ws_rel  = (const float*)d_in[12];
    const float* bs      = (const float*)d_in[13];
    const float* Ws_root = (const float*)d_in[14];
    const float* Wl1     = (const float*)d_in[15];
    const float* bl1     = (const float*)d_in[16];
    const float* Wl2     = (const float*)d_in[17];
    const float* bl2     = (const float*)d_in[18];

    char* ws = (char*)d_ws;
    size_t off = 0;
    auto alloc = [&](size_t bytes) -> void* {
        void* p = ws + off;
        off += (bytes + 255) & ~(size_t)255;
        return p;
    };
    u16*   XB    = (u16*)alloc((size_t)NN * 128 * 2);   // gemm input
    u16*   X2B   = (u16*)alloc((size_t)NN * 128 * 2);   // conv2 output (pre-gate)
    u16*   YB    = (u16*)alloc((size_t)NN * 256 * 2);   // gemm output
    u16*   WT    = (u16*)alloc(256 * 128 * 2);
    float* SREL  = (float*)alloc(NN * 4);
    float* SROOT = (float*)alloc(NN * 4);
    float* SCORE = (float*)alloc(NN * 4);
    float* GATE  = (float*)alloc(NN * 4);
    float* KEEP  = (float*)alloc(NN * 4);
    int*   DEG   = (int*)alloc(NN * 4);
    int*   NOFF  = (int*)alloc(NN * 4);
    int*   CUR   = (int*)alloc(NN * 4);
    int*   CSR   = (int*)alloc((size_t)EE * 4);
    float* XS    = (float*)alloc(BG * 384 * 4);
    (void)ws_size; (void)n_in; (void)in_sizes; (void)out_size;

    hipMemsetAsync(DEG, 0, NN * 4, stream);
    hipMemsetAsync(XS, 0, BG * 384 * 4, stream);

    // CSR build (by dst)
    deg_count_kernel<<<EE / 256, 256, 0, stream>>>(dst, DEG, EE);
    csr_offsets_kernel<<<BG, 256, 0, stream>>>(DEG, NOFF, CUR);
    csr_fill_kernel<<<EE / 256, 256, 0, stream>>>(src, dst, CUR, CSR, EE);

    // cast input to bf16
    cast_kernel<<<(NN * 128 / 4) / 256, 256, 0, stream>>>(x, XB, NN * 128 / 4);

    // ---- conv1 ----
    prep_w_kernel<<<128, 256, 0, stream>>>(W1_rel, W1_root, WT);
    gemm_kernel<<<dim3(NN / 128, 2), 256, 0, stream>>>(XB, WT, YB);
    agg_kernel<<<NN / 4, 256, 0, stream>>>(YB, CSR, NOFF, DEG, b1, nullptr, XB,
                                           nullptr, nullptr, nullptr, nullptr,
                                           XS, 0, 1.f / 1024.f);

    // ---- conv2 (+ fused score dots) ----
    prep_w_kernel<<<128, 256, 0, stream>>>(W2_rel, W2_root, WT);
    gemm_kernel<<<dim3(NN / 128, 2), 256, 0, stream>>>(XB, WT, YB);
    agg_kernel<<<NN / 4, 256, 0, stream>>>(YB, CSR, NOFF, DEG, b2, nullptr, X2B,
                                           Ws_rel, Ws_root, SREL, SROOT,
                                           XS, 128, 1.f / 1024.f);

    // ---- SAGPooling ----
    score_agg_kernel<<<NN / 256, 256, 0, stream>>>(SREL, SROOT, bs, CSR, NOFF, DEG, SCORE);
    topk_kernel<<<BG, 1024, 0, stream>>>(SCORE, KEEP, GATE);
    gate_bf16_kernel<<<(NN * 128 / 4) / 256, 256, 0, stream>>>(X2B, GATE, XB, NN * 128 / 4);

    // ---- conv3 (masked) ----
    prep_w_kernel<<<128, 256, 0, stream>>>(W3_rel, W3_root, WT);
    gemm_kernel<<<dim3(NN / 128, 2), 256, 0, stream>>>(XB, WT, YB);
    agg_kernel<<<NN / 4, 256, 0, stream>>>(YB, CSR, NOFF, DEG, b3, KEEP, nullptr,
                                           nullptr, nullptr, nullptr, nullptr,
                                           XS, 256, 1.f / (float)KKEEP);

    // ---- MLP head ----
    mlp_kernel<<<BG, 128, 0, stream>>>(XS, Wl1, bl1, Wl2, bl2, (float*)d_out);
}

// Round 3
// 349.789 us; speedup vs baseline: 1.4965x; 1.0188x over previous
//
#include <hip/hip_runtime.h>
#include <hip/hip_bf16.h>

#define NN 65536
#define EE 1048576
#define BG 64
#define NPGC 1024
#define KKEEP 820

typedef unsigned short u16;
typedef unsigned int u32;
typedef __attribute__((ext_vector_type(4))) float f32x4;
typedef __attribute__((ext_vector_type(8))) short bf16x8;

__device__ __forceinline__ float bfu_lo(u32 u) {  // low bf16 -> f32
    u32 x = u << 16;
    return __builtin_bit_cast(float, x);
}
__device__ __forceinline__ float bfu_hi(u32 u) {  // high bf16 -> f32
    u32 x = u & 0xffff0000u;
    return __builtin_bit_cast(float, x);
}
__device__ __forceinline__ u16 fbf(float f) {
    __hip_bfloat16 h = __float2bfloat16(f);
    return __builtin_bit_cast(u16, h);
}

// ---------------- CSR build ----------------
__global__ void deg_count_kernel(const int* __restrict__ dst, int* __restrict__ deg, int n) {
    int i = blockIdx.x * 256 + threadIdx.x;
    if (i < n) atomicAdd(&deg[dst[i]], 1);
}

// one block per graph: exclusive scan of 1024 degrees -> node offsets (graph base = g*16384)
__global__ __launch_bounds__(256) void csr_offsets_kernel(const int* __restrict__ deg,
                                                          int* __restrict__ noff,
                                                          int* __restrict__ cur) {
    __shared__ int part[256];
    int g = blockIdx.x, t = threadIdx.x;
    int base = g * NPGC;
    int v0 = deg[base + t * 4 + 0];
    int v1 = deg[base + t * 4 + 1];
    int v2 = deg[base + t * 4 + 2];
    int v3 = deg[base + t * 4 + 3];
    int tot = v0 + v1 + v2 + v3;
    part[t] = tot;
    __syncthreads();
    for (int d = 1; d < 256; d <<= 1) {
        int add = (t >= d) ? part[t - d] : 0;
        __syncthreads();
        part[t] += add;
        __syncthreads();
    }
    int excl = (t == 0) ? 0 : part[t - 1];
    int o = g * (NPGC * 16) + excl;
    int i0 = base + t * 4;
    noff[i0 + 0] = o;            cur[i0 + 0] = o;
    noff[i0 + 1] = o + v0;       cur[i0 + 1] = o + v0;
    noff[i0 + 2] = o + v0 + v1;  cur[i0 + 2] = o + v0 + v1;
    noff[i0 + 3] = o + v0 + v1 + v2; cur[i0 + 3] = o + v0 + v1 + v2;
}

__global__ void csr_fill_kernel(const int* __restrict__ src, const int* __restrict__ dst,
                                int* __restrict__ cur, int* __restrict__ csr, int n) {
    int i = blockIdx.x * 256 + threadIdx.x;
    if (i < n) {
        int p = atomicAdd(&cur[dst[i]], 1);
        csr[p] = src[i];
    }
}

// ---------------- casts ----------------
__global__ void cast_kernel(const float* __restrict__ in, u16* __restrict__ out, int n4) {
    int i = blockIdx.x * 256 + threadIdx.x;
    if (i >= n4) return;
    float4 v = reinterpret_cast<const float4*>(in)[i];
    u32 lo = (u32)fbf(v.x) | ((u32)fbf(v.y) << 16);
    u32 hi = (u32)fbf(v.z) | ((u32)fbf(v.w) << 16);
    uint2 o = {lo, hi};
    reinterpret_cast<uint2*>(out)[i] = o;
}

// bf16 features * per-node gate -> bf16
__global__ void gate_bf16_kernel(const u16* __restrict__ in, const float* __restrict__ gate,
                                 u16* __restrict__ out, int n4) {
    int i = blockIdx.x * 256 + threadIdx.x;
    if (i >= n4) return;
    uint2 v = reinterpret_cast<const uint2*>(in)[i];  // 4 bf16
    float g = gate[i >> 5];                           // 32 uint2 per node (128 feats)
    u32 lo = (u32)fbf(bfu_lo(v.x) * g) | ((u32)fbf(bfu_hi(v.x) * g) << 16);
    u32 hi = (u32)fbf(bfu_lo(v.y) * g) | ((u32)fbf(bfu_hi(v.y) * g) << 16);
    uint2 o = {lo, hi};
    reinterpret_cast<uint2*>(out)[i] = o;
}

// WT[col][k] = (col<128 ? Wrel[k][col] : Wroot[k][col-128]) as bf16, 256x128
__global__ void prep_w_kernel(const float* __restrict__ Wrel, const float* __restrict__ Wroot,
                              u16* __restrict__ WT) {
    int idx = blockIdx.x * 256 + threadIdx.x;  // 32768
    int col = idx >> 7, k = idx & 127;
    float v = (col < 128) ? Wrel[k * 128 + col] : Wroot[k * 128 + (col - 128)];
    WT[idx] = fbf(v);
}

// ---------------- GEMM: Y[N][256] = X[N][128] @ Wcat[128][256]  (bf16 in/out, fp32 acc)
__global__ __launch_bounds__(256, 2) void gemm_kernel(const u16* __restrict__ X,
                                                      const u16* __restrict__ WT,
                                                      u16* __restrict__ Y) {
    __shared__ u16 As[128][72];  // pitch 72 u16 = 144B (2-way bank alias = free)
    __shared__ u16 Bs[128][72];
    int rb = blockIdx.x * 128;
    int cb = blockIdx.y * 128;
    int tid = threadIdx.x;
    int lane = tid & 63, wid = tid >> 6;
    int wr = (wid >> 1) << 6, wc = (wid & 1) << 6;
    int lr = lane & 15, lk = (lane >> 4) << 3;
    f32x4 acc[4][4] = {};

    for (int half = 0; half < 2; ++half) {
        int k0 = half << 6;
        if (half) __syncthreads();
        for (int i = tid; i < 1024; i += 256) {
            int r = i >> 3, c = (i & 7) << 3;
            *reinterpret_cast<uint4*>(&As[r][c]) =
                *reinterpret_cast<const uint4*>(X + (rb + r) * 128 + k0 + c);
            *reinterpret_cast<uint4*>(&Bs[r][c]) =
                *reinterpret_cast<const uint4*>(WT + (cb + r) * 128 + k0 + c);
        }
        __syncthreads();
        for (int kk = 0; kk < 64; kk += 32) {
            bf16x8 a[4], b[4];
            for (int m = 0; m < 4; ++m)
                a[m] = *reinterpret_cast<const bf16x8*>(&As[wr + m * 16 + lr][kk + lk]);
            for (int n = 0; n < 4; ++n)
                b[n] = *reinterpret_cast<const bf16x8*>(&Bs[wc + n * 16 + lr][kk + lk]);
            for (int m = 0; m < 4; ++m)
                for (int n = 0; n < 4; ++n)
                    acc[m][n] = __builtin_amdgcn_mfma_f32_16x16x32_bf16(a[m], b[n], acc[m][n], 0, 0, 0);
        }
    }
    int orow0 = rb + wr + ((lane >> 4) << 2);
    int ocol0 = cb + wc + (lane & 15);
    for (int m = 0; m < 4; ++m)
        for (int n = 0; n < 4; ++n)
            for (int r = 0; r < 4; ++r)
                Y[(size_t)(orow0 + m * 16 + r) * 256 + ocol0 + n * 16] = fbf(acc[m][n][r]);
}

// ---------------- fused aggregate + combine + relu + pool (+score) ----------------
// Deep-pipelined gather: two 8-wide register groups, up to 16 loads in flight.
// XCD swizzle: XCD i owns graphs [8i, 8i+8) so gathers hit the private L2.
__global__ __launch_bounds__(256) void agg_kernel(const u16* __restrict__ Y,
                                                  const int* __restrict__ csr,
                                                  const int* __restrict__ noff,
                                                  const int* __restrict__ deg,
                                                  const float* __restrict__ bias,
                                                  const float* __restrict__ keep,
                                                  u16* __restrict__ outb,
                                                  const float* __restrict__ wsrel,
                                                  const float* __restrict__ wsroot,
                                                  float* __restrict__ srel,
                                                  float* __restrict__ sroot,
                                                  float* __restrict__ xs,
                                                  int base, float invdenom) {
    __shared__ float pool[4][128];
    // XCD-aware swizzle: 16384 blocks, 8 XCDs -> XCD i gets blocks [i*2048,(i+1)*2048)
    int blk = (blockIdx.x & 7) * 2048 + (blockIdx.x >> 3);
    int wid = threadIdx.x >> 6, lane = threadIdx.x & 63;
    int node = blk * 4 + wid;
    int off = noff[node], dg = deg[node];

    // issue root-part + bias loads early
    u32 vr = *reinterpret_cast<const u32*>(Y + (size_t)node * 256 + 128 + lane * 2);
    float2 bb = reinterpret_cast<const float2*>(bias)[lane];

    // lane-parallel neighbor index load (covers dg<=64)
    int sid = (lane < dg) ? csr[off + lane] : 0;
    float cnt;
    if (keep) {
        float kw = (lane < dg) ? keep[sid] : 0.f;
        for (int d = 1; d < 64; d <<= 1) kw += __shfl_xor(kw, d, 64);
        cnt = kw;
    } else {
        cnt = (float)dg;
    }

    int dgc = dg < 64 ? dg : 64;
    float a0 = 0.f, a1 = 0.f;

#define LOADG(buf, g)                                                                   \
    _Pragma("unroll") for (int j = 0; j < 8; ++j) {                                     \
        int s_ = __builtin_amdgcn_readlane(sid, (g) * 8 + j);                           \
        buf[j] = *reinterpret_cast<const u32*>(Y + (size_t)s_ * 256 + lane * 2);        \
    }
#define ACCG(buf, g)                                                                    \
    _Pragma("unroll") for (int j = 0; j < 8; ++j) {                                     \
        float w_ = ((g) * 8 + j < dgc) ? 1.f : 0.f;                                     \
        a0 += w_ * bfu_lo(buf[j]);                                                      \
        a1 += w_ * bfu_hi(buf[j]);                                                      \
    }

    if (dgc > 0) {
        u32 va[8], vb[8];
        int ng = (dgc + 7) >> 3;
        LOADG(va, 0)
        int g = 0;
        for (; g + 2 < ng; g += 2) {
            LOADG(vb, g + 1)
            ACCG(va, g)
            LOADG(va, g + 2)
            ACCG(vb, g + 1)
        }
        if (g + 1 < ng) {
            LOADG(vb, g + 1)
            ACCG(va, g)
            ACCG(vb, g + 1)
        } else {
            ACCG(va, g)
        }
    }
#undef LOADG
#undef ACCG

    for (int e = 64; e < dg; ++e) {  // astronomically rare: degree > 64
        int s = csr[off + e];
        if (keep) cnt += keep[s];
        u32 v = *reinterpret_cast<const u32*>(Y + (size_t)s * 256 + lane * 2);
        a0 += bfu_lo(v);
        a1 += bfu_hi(v);
    }

    float ki = keep ? keep[node] : 1.0f;
    float inv = ki / fmaxf(cnt, 1.0f);
    float r0 = fmaxf(a0 * inv + bb.x + bfu_lo(vr), 0.f);
    float r1 = fmaxf(a1 * inv + bb.y + bfu_hi(vr), 0.f);

    if (outb) {
        u32 p = ((u32)fbf(r1) << 16) | (u32)fbf(r0);
        *reinterpret_cast<u32*>(outb + (size_t)node * 128 + lane * 2) = p;
    }

    if (srel) {  // SAGPool score partial dots (conv2 only)
        float2 w0 = reinterpret_cast<const float2*>(wsrel)[lane];
        float2 w1 = reinterpret_cast<const float2*>(wsroot)[lane];
        float pr = r0 * w0.x + r1 * w0.y;
        float po = r0 * w1.x + r1 * w1.y;
        for (int d = 1; d < 64; d <<= 1) {
            pr += __shfl_xor(pr, d, 64);
            po += __shfl_xor(po, d, 64);
        }
        if (lane == 0) { srel[node] = pr; sroot[node] = po; }
    }

    // pool: LDS partial across the block's 4 nodes, then one atomic per feature
    float pw = keep ? ki : 1.0f;
    pool[wid][lane * 2] = r0 * pw;
    pool[wid][lane * 2 + 1] = r1 * pw;
    __syncthreads();
    int t = threadIdx.x;
    if (t < 128) {
        float s = pool[0][t] + pool[1][t] + pool[2][t] + pool[3][t];
        int g = blk >> 8;  // 256 blocks per graph (after swizzle)
        atomicAdd(&xs[g * 384 + base + t], s * invdenom);
    }
}

__global__ void score_agg_kernel(const float* __restrict__ srel, const float* __restrict__ sroot,
                                 const float* __restrict__ bs, const int* __restrict__ csr,
                                 const int* __restrict__ noff, const int* __restrict__ deg,
                                 float* __restrict__ score) {
    int i = blockIdx.x * 256 + threadIdx.x;
    if (i >= NN) return;
    int off = noff[i], dg = deg[i];
    float s = 0.f;
    for (int e = 0; e < dg; ++e) s += srel[csr[off + e]];
    score[i] = s / fmaxf((float)dg, 1.0f) + bs[0] + sroot[i];
}

// ---------------- per-graph top-K via bitonic sort (desc score, asc idx tiebreak)
__global__ __launch_bounds__(1024) void topk_kernel(const float* __restrict__ score,
                                                    float* __restrict__ keep,
                                                    float* __restrict__ gate) {
    __shared__ float sc[NPGC];
    __shared__ int si[NPGC];
    int g = blockIdx.x, t = threadIdx.x;
    sc[t] = score[g * NPGC + t];
    si[t] = t;
    __syncthreads();
    for (int k = 2; k <= NPGC; k <<= 1) {
        for (int j = k >> 1; j > 0; j >>= 1) {
            int ixj = t ^ j;
            if (ixj > t) {
                float a = sc[t], b = sc[ixj];
                int ai = si[t], bi = si[ixj];
                bool less = (a > b) || (a == b && ai < bi);  // "a precedes b" in desc order
                bool up = ((t & k) == 0);
                if (less != up) { sc[t] = b; sc[ixj] = a; si[t] = bi; si[ixj] = ai; }
            }
            __syncthreads();
        }
    }
    int node = g * NPGC + si[t];
    float kf = (t < KKEEP) ? 1.f : 0.f;
    keep[node] = kf;
    gate[node] = kf * tanhf(sc[t]);
}

// ---------------- MLP head + log_softmax (one block per graph)
__global__ __launch_bounds__(128) void mlp_kernel(const float* __restrict__ xs,
                                                  const float* __restrict__ Wl1,
                                                  const float* __restrict__ bl1,
                                                  const float* __restrict__ Wl2,
                                                  const float* __restrict__ bl2,
                                                  float* __restrict__ out) {
    __shared__ float xsl[384];
    __shared__ float hl[128];
    __shared__ float lg[10];
    int g = blockIdx.x, t = threadIdx.x;
    for (int i = t; i < 384; i += 128) xsl[i] = xs[g * 384 + i];
    __syncthreads();
    float h = bl1[t];
#pragma unroll 4
    for (int k = 0; k < 384; ++k) h += xsl[k] * Wl1[k * 128 + t];
    hl[t] = fmaxf(h, 0.f);
    __syncthreads();
    if (t < 10) {
        float l = bl2[t];
        for (int k = 0; k < 128; ++k) l += hl[k] * Wl2[k * 10 + t];
        lg[t] = l;
    }
    __syncthreads();
    if (t < 10) {
        float m = lg[0];
        for (int c = 1; c < 10; ++c) m = fmaxf(m, lg[c]);
        float s = 0.f;
        for (int c = 0; c < 10; ++c) s += expf(lg[c] - m);
        out[g * 10 + t] = lg[t] - m - logf(s);
    }
}

extern "C" void kernel_launch(void* const* d_in, const int* in_sizes, int n_in,
                              void* d_out, int out_size, void* d_ws, size_t ws_size,
                              hipStream_t stream) {
    const float* x       = (const float*)d_in[0];
    const int*   src     = (const int*)d_in[1];
    const int*   dst     = (const int*)d_in[2];
    const float* W1_rel  = (const float*)d_in[3];
    const float* b1      = (const float*)d_in[4];
    const float* W1_root = (const float*)d_in[5];
    const float* W2_rel  = (const float*)d_in[6];
    const float* b2      = (const float*)d_in[7];
    const float* W2_root = (const float*)d_in[8];
    const float* W3_rel  = (const float*)d_in[9];
    const float* b3      = (const float*)d_in[10];
    const float* W3_root = (const float*)d_in[11];
    const float* Ws_rel  = (const float*)d_in[12];
    const float* bs      = (const float*)d_in[13];
    const float* Ws_root = (const float*)d_in[14];
    const float* Wl1     = (const float*)d_in[15];
    const float* bl1     = (const float*)d_in[16];
    const float* Wl2     = (const float*)d_in[17];
    const float* bl2     = (const float*)d_in[18];

    char* ws = (char*)d_ws;
    size_t off = 0;
    auto alloc = [&](size_t bytes) -> void* {
        void* p = ws + off;
        off += (bytes + 255) & ~(size_t)255;
        return p;
    };
    u16*   XB    = (u16*)alloc((size_t)NN * 128 * 2);   // gemm input
    u16*   X2B   = (u16*)alloc((size_t)NN * 128 * 2);   // conv2 output (pre-gate)
    u16*   YB    = (u16*)alloc((size_t)NN * 256 * 2);   // gemm output
    u16*   WT    = (u16*)alloc(256 * 128 * 2);
    float* SREL  = (float*)alloc(NN * 4);
    float* SROOT = (float*)alloc(NN * 4);
    float* SCORE = (float*)alloc(NN * 4);
    float* GATE  = (float*)alloc(NN * 4);
    float* KEEP  = (float*)alloc(NN * 4);
    int*   DEG   = (int*)alloc(NN * 4);
    int*   NOFF  = (int*)alloc(NN * 4);
    int*   CUR   = (int*)alloc(NN * 4);
    int*   CSR   = (int*)alloc((size_t)EE * 4);
    float* XS    = (float*)alloc(BG * 384 * 4);
    (void)ws_size; (void)n_in; (void)in_sizes; (void)out_size;

    hipMemsetAsync(DEG, 0, NN * 4, stream);
    hipMemsetAsync(XS, 0, BG * 384 * 4, stream);

    // CSR build (by dst)
    deg_count_kernel<<<EE / 256, 256, 0, stream>>>(dst, DEG, EE);
    csr_offsets_kernel<<<BG, 256, 0, stream>>>(DEG, NOFF, CUR);
    csr_fill_kernel<<<EE / 256, 256, 0, stream>>>(src, dst, CUR, CSR, EE);

    // cast input to bf16
    cast_kernel<<<(NN * 128 / 4) / 256, 256, 0, stream>>>(x, XB, NN * 128 / 4);

    // ---- conv1 ----
    prep_w_kernel<<<128, 256, 0, stream>>>(W1_rel, W1_root, WT);
    gemm_kernel<<<dim3(NN / 128, 2), 256, 0, stream>>>(XB, WT, YB);
    agg_kernel<<<NN / 4, 256, 0, stream>>>(YB, CSR, NOFF, DEG, b1, nullptr, XB,
                                           nullptr, nullptr, nullptr, nullptr,
                                           XS, 0, 1.f / 1024.f);

    // ---- conv2 (+ fused score dots) ----
    prep_w_kernel<<<128, 256, 0, stream>>>(W2_rel, W2_root, WT);
    gemm_kernel<<<dim3(NN / 128, 2), 256, 0, stream>>>(XB, WT, YB);
    agg_kernel<<<NN / 4, 256, 0, stream>>>(YB, CSR, NOFF, DEG, b2, nullptr, X2B,
                                           Ws_rel, Ws_root, SREL, SROOT,
                                           XS, 128, 1.f / 1024.f);

    // ---- SAGPooling ----
    score_agg_kernel<<<NN / 256, 256, 0, stream>>>(SREL, SROOT, bs, CSR, NOFF, DEG, SCORE);
    topk_kernel<<<BG, 1024, 0, stream>>>(SCORE, KEEP, GATE);
    gate_bf16_kernel<<<(NN * 128 / 4) / 256, 256, 0, stream>>>(X2B, GATE, XB, NN * 128 / 4);

    // ---- conv3 (masked) ----
    prep_w_kernel<<<128, 256, 0, stream>>>(W3_rel, W3_root, WT);
    gemm_kernel<<<dim3(NN / 128, 2), 256, 0, stream>>>(XB, WT, YB);
    agg_kernel<<<NN / 4, 256, 0, stream>>>(YB, CSR, NOFF, DEG, b3, KEEP, nullptr,
                                           nullptr, nullptr, nullptr, nullptr,
                                           XS, 256, 1.f / (float)KKEEP);

    // ---- MLP head ----
    mlp_kernel<<<BG, 128, 0, stream>>>(XS, Wl1, bl1, Wl2, bl2, (float*)d_out);
}

// Round 4
// 292.575 us; speedup vs baseline: 1.7892x; 1.1956x over previous
//
#include <hip/hip_runtime.h>
#include <hip/hip_bf16.h>

#define NN 65536
#define EE 1048576
#define BG 64
#define NPGC 1024
#define KKEEP 820

typedef unsigned short u16;
typedef unsigned int u32;
typedef __attribute__((ext_vector_type(4))) float f32x4;
typedef __attribute__((ext_vector_type(8))) short bf16x8;

__device__ __forceinline__ float bfu_lo(u32 u) {  // low bf16 -> f32
    u32 x = u << 16;
    return __builtin_bit_cast(float, x);
}
__device__ __forceinline__ float bfu_hi(u32 u) {  // high bf16 -> f32
    u32 x = u & 0xffff0000u;
    return __builtin_bit_cast(float, x);
}
__device__ __forceinline__ u16 fbf(float f) {
    __hip_bfloat16 h = __float2bfloat16(f);
    return __builtin_bit_cast(u16, h);
}

// ---------------- CSR build ----------------
__global__ void deg_count_kernel(const int* __restrict__ dst, int* __restrict__ deg, int n) {
    int i = blockIdx.x * 256 + threadIdx.x;
    if (i < n) atomicAdd(&deg[dst[i]], 1);
}

__global__ __launch_bounds__(256) void csr_offsets_kernel(const int* __restrict__ deg,
                                                          int* __restrict__ noff,
                                                          int* __restrict__ cur) {
    __shared__ int part[256];
    int g = blockIdx.x, t = threadIdx.x;
    int base = g * NPGC;
    int v0 = deg[base + t * 4 + 0];
    int v1 = deg[base + t * 4 + 1];
    int v2 = deg[base + t * 4 + 2];
    int v3 = deg[base + t * 4 + 3];
    int tot = v0 + v1 + v2 + v3;
    part[t] = tot;
    __syncthreads();
    for (int d = 1; d < 256; d <<= 1) {
        int add = (t >= d) ? part[t - d] : 0;
        __syncthreads();
        part[t] += add;
        __syncthreads();
    }
    int excl = (t == 0) ? 0 : part[t - 1];
    int o = g * (NPGC * 16) + excl;
    int i0 = base + t * 4;
    noff[i0 + 0] = o;            cur[i0 + 0] = o;
    noff[i0 + 1] = o + v0;       cur[i0 + 1] = o + v0;
    noff[i0 + 2] = o + v0 + v1;  cur[i0 + 2] = o + v0 + v1;
    noff[i0 + 3] = o + v0 + v1 + v2; cur[i0 + 3] = o + v0 + v1 + v2;
}

__global__ void csr_fill_kernel(const int* __restrict__ src, const int* __restrict__ dst,
                                int* __restrict__ cur, int* __restrict__ csr, int n) {
    int i = blockIdx.x * 256 + threadIdx.x;
    if (i < n) {
        int p = atomicAdd(&cur[dst[i]], 1);
        csr[p] = src[i];
    }
}

// ---------------- casts ----------------
__global__ void cast_kernel(const float* __restrict__ in, u16* __restrict__ out, int n4) {
    int i = blockIdx.x * 256 + threadIdx.x;
    if (i >= n4) return;
    float4 v = reinterpret_cast<const float4*>(in)[i];
    u32 lo = (u32)fbf(v.x) | ((u32)fbf(v.y) << 16);
    u32 hi = (u32)fbf(v.z) | ((u32)fbf(v.w) << 16);
    uint2 o = {lo, hi};
    reinterpret_cast<uint2*>(out)[i] = o;
}

__global__ void gate_bf16_kernel(const u16* __restrict__ in, const float* __restrict__ gate,
                                 u16* __restrict__ out, int n4) {
    int i = blockIdx.x * 256 + threadIdx.x;
    if (i >= n4) return;
    uint2 v = reinterpret_cast<const uint2*>(in)[i];  // 4 bf16
    float g = gate[i >> 5];                           // 32 uint2 per node (128 feats)
    u32 lo = (u32)fbf(bfu_lo(v.x) * g) | ((u32)fbf(bfu_hi(v.x) * g) << 16);
    u32 hi = (u32)fbf(bfu_lo(v.y) * g) | ((u32)fbf(bfu_hi(v.y) * g) << 16);
    uint2 o = {lo, hi};
    reinterpret_cast<uint2*>(out)[i] = o;
}

// WT[l][col][k]: 3 weight sets at once. l = blockIdx.y.
__global__ void prep_w_kernel(const float* __restrict__ Wr1, const float* __restrict__ Wo1,
                              const float* __restrict__ Wr2, const float* __restrict__ Wo2,
                              const float* __restrict__ Wr3, const float* __restrict__ Wo3,
                              u16* __restrict__ WT) {
    int l = blockIdx.y;
    const float* Wrel = l == 0 ? Wr1 : (l == 1 ? Wr2 : Wr3);
    const float* Wroot = l == 0 ? Wo1 : (l == 1 ? Wo2 : Wo3);
    int idx = blockIdx.x * 256 + threadIdx.x;  // 32768
    int col = idx >> 7, k = idx & 127;
    float v = (col < 128) ? Wrel[k * 128 + col] : Wroot[k * 128 + (col - 128)];
    WT[l * 32768 + idx] = fbf(v);
}

// ---------------- GEMM: Y[N][256] = X[N][128] @ Wcat[128][256]  (bf16 in/out, fp32 acc)
__global__ __launch_bounds__(256, 2) void gemm_kernel(const u16* __restrict__ X,
                                                      const u16* __restrict__ WT,
                                                      u16* __restrict__ Y) {
    __shared__ u16 As[128][72];
    __shared__ u16 Bs[128][72];
    int rb = blockIdx.x * 128;
    int cb = blockIdx.y * 128;
    int tid = threadIdx.x;
    int lane = tid & 63, wid = tid >> 6;
    int wr = (wid >> 1) << 6, wc = (wid & 1) << 6;
    int lr = lane & 15, lk = (lane >> 4) << 3;
    f32x4 acc[4][4] = {};

    for (int half = 0; half < 2; ++half) {
        int k0 = half << 6;
        if (half) __syncthreads();
        for (int i = tid; i < 1024; i += 256) {
            int r = i >> 3, c = (i & 7) << 3;
            *reinterpret_cast<uint4*>(&As[r][c]) =
                *reinterpret_cast<const uint4*>(X + (rb + r) * 128 + k0 + c);
            *reinterpret_cast<uint4*>(&Bs[r][c]) =
                *reinterpret_cast<const uint4*>(WT + (cb + r) * 128 + k0 + c);
        }
        __syncthreads();
        for (int kk = 0; kk < 64; kk += 32) {
            bf16x8 a[4], b[4];
            for (int m = 0; m < 4; ++m)
                a[m] = *reinterpret_cast<const bf16x8*>(&As[wr + m * 16 + lr][kk + lk]);
            for (int n = 0; n < 4; ++n)
                b[n] = *reinterpret_cast<const bf16x8*>(&Bs[wc + n * 16 + lr][kk + lk]);
            for (int m = 0; m < 4; ++m)
                for (int n = 0; n < 4; ++n)
                    acc[m][n] = __builtin_amdgcn_mfma_f32_16x16x32_bf16(a[m], b[n], acc[m][n], 0, 0, 0);
        }
    }
    int orow0 = rb + wr + ((lane >> 4) << 2);
    int ocol0 = cb + wc + (lane & 15);
    for (int m = 0; m < 4; ++m)
        for (int n = 0; n < 4; ++n)
            for (int r = 0; r < 4; ++r)
                Y[(size_t)(orow0 + m * 16 + r) * 256 + ocol0 + n * 16] = fbf(acc[m][n][r]);
}

// full-group accumulate (no mask) / tail-group (masked) — wave-uniform branch
__device__ __forceinline__ void accg(const u32* buf, int g8, int dgc, float& a0, float& a1) {
    if (g8 + 8 <= dgc) {
#pragma unroll
        for (int j = 0; j < 8; ++j) { a0 += bfu_lo(buf[j]); a1 += bfu_hi(buf[j]); }
    } else {
#pragma unroll
        for (int j = 0; j < 8; ++j) {
            if (g8 + j < dgc) { a0 += bfu_lo(buf[j]); a1 += bfu_hi(buf[j]); }
        }
    }
}

// ---------------- fused aggregate + combine + relu + pool (+score) ----------------
// Pool partials go to 16 buckets per graph (16-way atomic contention instead of 256).
__global__ __launch_bounds__(256) void agg_kernel(const u16* __restrict__ Y,
                                                  const int* __restrict__ csr,
                                                  const int* __restrict__ noff,
                                                  const int* __restrict__ deg,
                                                  const float* __restrict__ bias,
                                                  const float* __restrict__ keep,
                                                  u16* __restrict__ outb,
                                                  const float* __restrict__ wsrel,
                                                  const float* __restrict__ wsroot,
                                                  float* __restrict__ srel,
                                                  float* __restrict__ sroot,
                                                  float* __restrict__ xsp,
                                                  int base, float invdenom) {
    __shared__ float pool[4][128];
    // XCD-aware swizzle: 16384 blocks, 8 XCDs -> XCD i gets blocks [i*2048,(i+1)*2048)
    int blk = (blockIdx.x & 7) * 2048 + (blockIdx.x >> 3);
    int wid = threadIdx.x >> 6, lane = threadIdx.x & 63;
    int node = blk * 4 + wid;

    float r0 = 0.f, r1 = 0.f;
    float ki = keep ? keep[node] : 1.0f;
    bool skip = keep && (ki == 0.f);  // wave-uniform: conv3 drops non-kept nodes

    if (!skip) {
        int off = noff[node], dg = deg[node];
        u32 vr = *reinterpret_cast<const u32*>(Y + (size_t)node * 256 + 128 + lane * 2);
        float2 bb = reinterpret_cast<const float2*>(bias)[lane];

        int sid = (lane < dg) ? csr[off + lane] : 0;
        float cnt;
        if (keep) {
            float kw = (lane < dg) ? keep[sid] : 0.f;
            for (int d = 1; d < 64; d <<= 1) kw += __shfl_xor(kw, d, 64);
            cnt = kw;
        } else {
            cnt = (float)dg;
        }

        int dgc = dg < 64 ? dg : 64;
        float a0 = 0.f, a1 = 0.f;

#define LOADG(buf, g)                                                                   \
    _Pragma("unroll") for (int j = 0; j < 8; ++j) {                                     \
        int s_ = __builtin_amdgcn_readlane(sid, (g) * 8 + j);                           \
        buf[j] = *reinterpret_cast<const u32*>(Y + (size_t)s_ * 256 + lane * 2);        \
    }

        if (dgc > 0) {
            u32 va[8], vb[8];
            int ng = (dgc + 7) >> 3;
            LOADG(va, 0)
            int g = 0;
            for (; g + 2 < ng; g += 2) {
                LOADG(vb, g + 1)
                accg(va, g * 8, dgc, a0, a1);
                LOADG(va, g + 2)
                accg(vb, (g + 1) * 8, dgc, a0, a1);
            }
            if (g + 1 < ng) {
                LOADG(vb, g + 1)
                accg(va, g * 8, dgc, a0, a1);
                accg(vb, (g + 1) * 8, dgc, a0, a1);
            } else {
                accg(va, g * 8, dgc, a0, a1);
            }
        }
#undef LOADG

        for (int e = 64; e < dg; ++e) {  // astronomically rare: degree > 64
            int s = csr[off + e];
            if (keep) cnt += keep[s];
            u32 v = *reinterpret_cast<const u32*>(Y + (size_t)s * 256 + lane * 2);
            a0 += bfu_lo(v);
            a1 += bfu_hi(v);
        }

        float inv = ki / fmaxf(cnt, 1.0f);
        r0 = fmaxf(a0 * inv + bb.x + bfu_lo(vr), 0.f);
        r1 = fmaxf(a1 * inv + bb.y + bfu_hi(vr), 0.f);

        if (outb) {
            u32 p = ((u32)fbf(r1) << 16) | (u32)fbf(r0);
            *reinterpret_cast<u32*>(outb + (size_t)node * 128 + lane * 2) = p;
        }

        if (srel) {  // SAGPool score partial dots (conv2 only)
            float2 w0 = reinterpret_cast<const float2*>(wsrel)[lane];
            float2 w1 = reinterpret_cast<const float2*>(wsroot)[lane];
            float pr = r0 * w0.x + r1 * w0.y;
            float po = r0 * w1.x + r1 * w1.y;
            for (int d = 1; d < 64; d <<= 1) {
                pr += __shfl_xor(pr, d, 64);
                po += __shfl_xor(po, d, 64);
            }
            if (lane == 0) { srel[node] = pr; sroot[node] = po; }
        }
    }

    // pool: LDS partial across the block's 4 nodes, then one atomic per feature into
    // this block's bucket (16 buckets per graph -> 16-way contention)
    pool[wid][lane * 2] = r0;      // conv3: r already includes ki gate only for output;
    pool[wid][lane * 2 + 1] = r1;  // pool weight for conv3 is ki, and r==0 when ki==0
    __syncthreads();
    int t = threadIdx.x;
    if (t < 128) {
        float s = pool[0][t] + pool[1][t] + pool[2][t] + pool[3][t];
        int g = blk >> 8;              // 256 blocks per graph (after swizzle)
        int bucket = blk & 15;
        atomicAdd(&xsp[(g * 16 + bucket) * 384 + base + t], s * invdenom);
    }
}

__global__ void score_agg_kernel(const float* __restrict__ srel, const float* __restrict__ sroot,
                                 const float* __restrict__ bs, const int* __restrict__ csr,
                                 const int* __restrict__ noff, const int* __restrict__ deg,
                                 float* __restrict__ score) {
    int i = blockIdx.x * 256 + threadIdx.x;
    if (i >= NN) return;
    int off = noff[i], dg = deg[i];
    float s = 0.f;
    for (int e = 0; e < dg; ++e) s += srel[csr[off + e]];
    score[i] = s / fmaxf((float)dg, 1.0f) + bs[0] + sroot[i];
}

// ---------------- per-graph top-K via bitonic sort (desc score, asc idx tiebreak)
__global__ __launch_bounds__(1024) void topk_kernel(const float* __restrict__ score,
                                                    float* __restrict__ keep,
                                                    float* __restrict__ gate) {
    __shared__ float sc[NPGC];
    __shared__ int si[NPGC];
    int g = blockIdx.x, t = threadIdx.x;
    sc[t] = score[g * NPGC + t];
    si[t] = t;
    __syncthreads();
    for (int k = 2; k <= NPGC; k <<= 1) {
        for (int j = k >> 1; j > 0; j >>= 1) {
            int ixj = t ^ j;
            if (ixj > t) {
                float a = sc[t], b = sc[ixj];
                int ai = si[t], bi = si[ixj];
                bool less = (a > b) || (a == b && ai < bi);
                bool up = ((t & k) == 0);
                if (less != up) { sc[t] = b; sc[ixj] = a; si[t] = bi; si[ixj] = ai; }
            }
            __syncthreads();
        }
    }
    int node = g * NPGC + si[t];
    float kf = (t < KKEEP) ? 1.f : 0.f;
    keep[node] = kf;
    gate[node] = kf * tanhf(sc[t]);
}

// ---------------- MLP head + log_softmax (one block per graph); reduces 16 pool buckets
__global__ __launch_bounds__(128) void mlp_kernel(const float* __restrict__ xsp,
                                                  const float* __restrict__ Wl1,
                                                  const float* __restrict__ bl1,
                                                  const float* __restrict__ Wl2,
                                                  const float* __restrict__ bl2,
                                                  float* __restrict__ out) {
    __shared__ float xsl[384];
    __shared__ float hl[128];
    __shared__ float lg[10];
    int g = blockIdx.x, t = threadIdx.x;
    for (int i = t; i < 384; i += 128) {
        float s = 0.f;
#pragma unroll
        for (int b = 0; b < 16; ++b) s += xsp[(g * 16 + b) * 384 + i];
        xsl[i] = s;
    }
    __syncthreads();
    float h = bl1[t];
#pragma unroll 4
    for (int k = 0; k < 384; ++k) h += xsl[k] * Wl1[k * 128 + t];
    hl[t] = fmaxf(h, 0.f);
    __syncthreads();
    if (t < 10) {
        float l = bl2[t];
        for (int k = 0; k < 128; ++k) l += hl[k] * Wl2[k * 10 + t];
        lg[t] = l;
    }
    __syncthreads();
    if (t < 10) {
        float m = lg[0];
        for (int c = 1; c < 10; ++c) m = fmaxf(m, lg[c]);
        float s = 0.f;
        for (int c = 0; c < 10; ++c) s += expf(lg[c] - m);
        out[g * 10 + t] = lg[t] - m - logf(s);
    }
}

extern "C" void kernel_launch(void* const* d_in, const int* in_sizes, int n_in,
                              void* d_out, int out_size, void* d_ws, size_t ws_size,
                              hipStream_t stream) {
    const float* x       = (const float*)d_in[0];
    const int*   src     = (const int*)d_in[1];
    const int*   dst     = (const int*)d_in[2];
    const float* W1_rel  = (const float*)d_in[3];
    const float* b1      = (const float*)d_in[4];
    const float* W1_root = (const float*)d_in[5];
    const float* W2_rel  = (const float*)d_in[6];
    const float* b2      = (const float*)d_in[7];
    const float* W2_root = (const float*)d_in[8];
    const float* W3_rel  = (const float*)d_in[9];
    const float* b3      = (const float*)d_in[10];
    const float* W3_root = (const float*)d_in[11];
    const float* Ws_rel  = (const float*)d_in[12];
    const float* bs      = (const float*)d_in[13];
    const float* Ws_root = (const float*)d_in[14];
    const float* Wl1     = (const float*)d_in[15];
    const float* bl1     = (const float*)d_in[16];
    const float* Wl2     = (const float*)d_in[17];
    const float* bl2     = (const float*)d_in[18];

    char* ws = (char*)d_ws;
    size_t off = 0;
    auto alloc = [&](size_t bytes) -> void* {
        void* p = ws + off;
        off += (bytes + 255) & ~(size_t)255;
        return p;
    };
    u16*   XB    = (u16*)alloc((size_t)NN * 128 * 2);   // gemm input
    u16*   X2B   = (u16*)alloc((size_t)NN * 128 * 2);   // conv2 output (pre-gate)
    u16*   YB    = (u16*)alloc((size_t)NN * 256 * 2);   // gemm output
    u16*   WT    = (u16*)alloc(3 * 256 * 128 * 2);      // 3 weight sets
    float* SREL  = (float*)alloc(NN * 4);
    float* SROOT = (float*)alloc(NN * 4);
    float* SCORE = (float*)alloc(NN * 4);
    float* GATE  = (float*)alloc(NN * 4);
    float* KEEP  = (float*)alloc(NN * 4);
    int*   DEG   = (int*)alloc(NN * 4);
    int*   NOFF  = (int*)alloc(NN * 4);
    int*   CUR   = (int*)alloc(NN * 4);
    int*   CSR   = (int*)alloc((size_t)EE * 4);
    float* XSP   = (float*)alloc((size_t)BG * 16 * 384 * 4);  // bucketed pool partials
    (void)ws_size; (void)n_in; (void)in_sizes; (void)out_size;

    hipMemsetAsync(DEG, 0, NN * 4, stream);
    hipMemsetAsync(XSP, 0, (size_t)BG * 16 * 384 * 4, stream);

    // CSR build (by dst)
    deg_count_kernel<<<EE / 256, 256, 0, stream>>>(dst, DEG, EE);
    csr_offsets_kernel<<<BG, 256, 0, stream>>>(DEG, NOFF, CUR);
    csr_fill_kernel<<<EE / 256, 256, 0, stream>>>(src, dst, CUR, CSR, EE);

    // cast input to bf16 + prep all 3 weight sets
    cast_kernel<<<(NN * 128 / 4) / 256, 256, 0, stream>>>(x, XB, NN * 128 / 4);
    prep_w_kernel<<<dim3(128, 3), 256, 0, stream>>>(W1_rel, W1_root, W2_rel, W2_root,
                                                    W3_rel, W3_root, WT);

    // ---- conv1 ----
    gemm_kernel<<<dim3(NN / 128, 2), 256, 0, stream>>>(XB, WT, YB);
    agg_kernel<<<NN / 4, 256, 0, stream>>>(YB, CSR, NOFF, DEG, b1, nullptr, XB,
                                           nullptr, nullptr, nullptr, nullptr,
                                           XSP, 0, 1.f / 1024.f);

    // ---- conv2 (+ fused score dots) ----
    gemm_kernel<<<dim3(NN / 128, 2), 256, 0, stream>>>(XB, WT + 32768, YB);
    agg_kernel<<<NN / 4, 256, 0, stream>>>(YB, CSR, NOFF, DEG, b2, nullptr, X2B,
                                           Ws_rel, Ws_root, SREL, SROOT,
                                           XSP, 128, 1.f / 1024.f);

    // ---- SAGPooling ----
    score_agg_kernel<<<NN / 256, 256, 0, stream>>>(SREL, SROOT, bs, CSR, NOFF, DEG, SCORE);
    topk_kernel<<<BG, 1024, 0, stream>>>(SCORE, KEEP, GATE);
    gate_bf16_kernel<<<(NN * 128 / 4) / 256, 256, 0, stream>>>(X2B, GATE, XB, NN * 128 / 4);

    // ---- conv3 (masked) ----
    gemm_kernel<<<dim3(NN / 128, 2), 256, 0, stream>>>(XB, WT + 65536, YB);
    agg_kernel<<<NN / 4, 256, 0, stream>>>(YB, CSR, NOFF, DEG, b3, KEEP, nullptr,
                                           nullptr, nullptr, nullptr, nullptr,
                                           XSP, 256, 1.f / (float)KKEEP);

    // ---- MLP head ----
    mlp_kernel<<<BG, 128, 0, stream>>>(XSP, Wl1, bl1, Wl2, bl2, (float*)d_out);
}

// Round 5
// 269.913 us; speedup vs baseline: 1.9394x; 1.0840x over previous
//
#include <hip/hip_runtime.h>
#include <hip/hip_bf16.h>

#define NN 65536
#define EE 1048576
#define BG 64
#define NPGC 1024
#define KKEEP 820

typedef unsigned short u16;
typedef unsigned int u32;
typedef __attribute__((ext_vector_type(4))) float f32x4;
typedef __attribute__((ext_vector_type(8))) short bf16x8;

__device__ __forceinline__ float bfu_lo(u32 u) {  // low bf16 -> f32
    u32 x = u << 16;
    return __builtin_bit_cast(float, x);
}
__device__ __forceinline__ float bfu_hi(u32 u) {  // high bf16 -> f32
    u32 x = u & 0xffff0000u;
    return __builtin_bit_cast(float, x);
}
__device__ __forceinline__ u16 fbf(float f) {
    __hip_bfloat16 h = __float2bfloat16(f);
    return __builtin_bit_cast(u16, h);
}

// ---------------- CSR build ----------------
__global__ void deg_count_kernel(const int* __restrict__ dst, int* __restrict__ deg, int n) {
    int i = blockIdx.x * 256 + threadIdx.x;
    if (i < n) atomicAdd(&deg[dst[i]], 1);
}

__global__ __launch_bounds__(256) void csr_offsets_kernel(const int* __restrict__ deg,
                                                          int* __restrict__ noff,
                                                          int* __restrict__ cur) {
    __shared__ int part[256];
    int g = blockIdx.x, t = threadIdx.x;
    int base = g * NPGC;
    int v0 = deg[base + t * 4 + 0];
    int v1 = deg[base + t * 4 + 1];
    int v2 = deg[base + t * 4 + 2];
    int v3 = deg[base + t * 4 + 3];
    int tot = v0 + v1 + v2 + v3;
    part[t] = tot;
    __syncthreads();
    for (int d = 1; d < 256; d <<= 1) {
        int add = (t >= d) ? part[t - d] : 0;
        __syncthreads();
        part[t] += add;
        __syncthreads();
    }
    int excl = (t == 0) ? 0 : part[t - 1];
    int o = g * (NPGC * 16) + excl;
    int i0 = base + t * 4;
    noff[i0 + 0] = o;            cur[i0 + 0] = o;
    noff[i0 + 1] = o + v0;       cur[i0 + 1] = o + v0;
    noff[i0 + 2] = o + v0 + v1;  cur[i0 + 2] = o + v0 + v1;
    noff[i0 + 3] = o + v0 + v1 + v2; cur[i0 + 3] = o + v0 + v1 + v2;
}

__global__ void csr_fill_kernel(const int* __restrict__ src, const int* __restrict__ dst,
                                int* __restrict__ cur, int* __restrict__ csr, int n) {
    int i = blockIdx.x * 256 + threadIdx.x;
    if (i < n) {
        int p = atomicAdd(&cur[dst[i]], 1);
        csr[p] = src[i];
    }
}

// ---------------- casts ----------------
__global__ void cast_kernel(const float* __restrict__ in, u16* __restrict__ out, int n4) {
    int i = blockIdx.x * 256 + threadIdx.x;
    if (i >= n4) return;
    float4 v = reinterpret_cast<const float4*>(in)[i];
    u32 lo = (u32)fbf(v.x) | ((u32)fbf(v.y) << 16);
    u32 hi = (u32)fbf(v.z) | ((u32)fbf(v.w) << 16);
    uint2 o = {lo, hi};
    reinterpret_cast<uint2*>(out)[i] = o;
}

__global__ void gate_bf16_kernel(const u16* __restrict__ in, const float* __restrict__ gate,
                                 u16* __restrict__ out, int n4) {
    int i = blockIdx.x * 256 + threadIdx.x;
    if (i >= n4) return;
    uint2 v = reinterpret_cast<const uint2*>(in)[i];  // 4 bf16
    float g = gate[i >> 5];                           // 32 uint2 per node (128 feats)
    u32 lo = (u32)fbf(bfu_lo(v.x) * g) | ((u32)fbf(bfu_hi(v.x) * g) << 16);
    u32 hi = (u32)fbf(bfu_lo(v.y) * g) | ((u32)fbf(bfu_hi(v.y) * g) << 16);
    uint2 o = {lo, hi};
    reinterpret_cast<uint2*>(out)[i] = o;
}

// WT[l][col][k]: 3 weight sets at once. l = blockIdx.y.
__global__ void prep_w_kernel(const float* __restrict__ Wr1, const float* __restrict__ Wo1,
                              const float* __restrict__ Wr2, const float* __restrict__ Wo2,
                              const float* __restrict__ Wr3, const float* __restrict__ Wo3,
                              u16* __restrict__ WT) {
    int l = blockIdx.y;
    const float* Wrel = l == 0 ? Wr1 : (l == 1 ? Wr2 : Wr3);
    const float* Wroot = l == 0 ? Wo1 : (l == 1 ? Wo2 : Wo3);
    int idx = blockIdx.x * 256 + threadIdx.x;  // 32768
    int col = idx >> 7, k = idx & 127;
    float v = (col < 128) ? Wrel[k * 128 + col] : Wroot[k * 128 + (col - 128)];
    WT[l * 32768 + idx] = fbf(v);
}

// ---------------- GEMM: Y[N][256] = X[N][128] @ Wcat[128][256]  (bf16 in/out, fp32 acc)
__global__ __launch_bounds__(256, 2) void gemm_kernel(const u16* __restrict__ X,
                                                      const u16* __restrict__ WT,
                                                      u16* __restrict__ Y) {
    __shared__ u16 As[128][72];
    __shared__ u16 Bs[128][72];
    int rb = blockIdx.x * 128;
    int cb = blockIdx.y * 128;
    int tid = threadIdx.x;
    int lane = tid & 63, wid = tid >> 6;
    int wr = (wid >> 1) << 6, wc = (wid & 1) << 6;
    int lr = lane & 15, lk = (lane >> 4) << 3;
    f32x4 acc[4][4] = {};

    for (int half = 0; half < 2; ++half) {
        int k0 = half << 6;
        if (half) __syncthreads();
        for (int i = tid; i < 1024; i += 256) {
            int r = i >> 3, c = (i & 7) << 3;
            *reinterpret_cast<uint4*>(&As[r][c]) =
                *reinterpret_cast<const uint4*>(X + (rb + r) * 128 + k0 + c);
            *reinterpret_cast<uint4*>(&Bs[r][c]) =
                *reinterpret_cast<const uint4*>(WT + (cb + r) * 128 + k0 + c);
        }
        __syncthreads();
        for (int kk = 0; kk < 64; kk += 32) {
            bf16x8 a[4], b[4];
            for (int m = 0; m < 4; ++m)
                a[m] = *reinterpret_cast<const bf16x8*>(&As[wr + m * 16 + lr][kk + lk]);
            for (int n = 0; n < 4; ++n)
                b[n] = *reinterpret_cast<const bf16x8*>(&Bs[wc + n * 16 + lr][kk + lk]);
            for (int m = 0; m < 4; ++m)
                for (int n = 0; n < 4; ++n)
                    acc[m][n] = __builtin_amdgcn_mfma_f32_16x16x32_bf16(a[m], b[n], acc[m][n], 0, 0, 0);
        }
    }
    int orow0 = rb + wr + ((lane >> 4) << 2);
    int ocol0 = cb + wc + (lane & 15);
    for (int m = 0; m < 4; ++m)
        for (int n = 0; n < 4; ++n)
            for (int r = 0; r < 4; ++r)
                Y[(size_t)(orow0 + m * 16 + r) * 256 + ocol0 + n * 16] = fbf(acc[m][n][r]);
}

// full-group accumulate (no mask) / tail-group (masked) — wave-uniform branch
__device__ __forceinline__ void accg(const u32* buf, int g8, int dgc, float& a0, float& a1) {
    if (g8 + 8 <= dgc) {
#pragma unroll
        for (int j = 0; j < 8; ++j) { a0 += bfu_lo(buf[j]); a1 += bfu_hi(buf[j]); }
    } else {
#pragma unroll
        for (int j = 0; j < 8; ++j) {
            if (g8 + j < dgc) { a0 += bfu_lo(buf[j]); a1 += bfu_hi(buf[j]); }
        }
    }
}

// ---------------- fused aggregate + combine + relu + pool (+score) ----------------
__global__ __launch_bounds__(256) void agg_kernel(const u16* __restrict__ Y,
                                                  const int* __restrict__ csr,
                                                  const int* __restrict__ noff,
                                                  const int* __restrict__ deg,
                                                  const float* __restrict__ bias,
                                                  const float* __restrict__ keep,
                                                  u16* __restrict__ outb,
                                                  const float* __restrict__ wsrel,
                                                  const float* __restrict__ wsroot,
                                                  float* __restrict__ srel,
                                                  float* __restrict__ sroot,
                                                  float* __restrict__ xsp,
                                                  int base, float invdenom) {
    __shared__ float pool[4][128];
    // XCD-aware swizzle: 16384 blocks, 8 XCDs -> XCD i gets blocks [i*2048,(i+1)*2048)
    int blk = (blockIdx.x & 7) * 2048 + (blockIdx.x >> 3);
    int wid = threadIdx.x >> 6, lane = threadIdx.x & 63;
    int node = blk * 4 + wid;

    float r0 = 0.f, r1 = 0.f;
    float ki = keep ? keep[node] : 1.0f;
    bool skip = keep && (ki == 0.f);  // wave-uniform: conv3 drops non-kept nodes

    if (!skip) {
        int off = noff[node], dg = deg[node];
        u32 vr = *reinterpret_cast<const u32*>(Y + (size_t)node * 256 + 128 + lane * 2);
        float2 bb = reinterpret_cast<const float2*>(bias)[lane];

        int sid = (lane < dg) ? csr[off + lane] : 0;
        float cnt;
        if (keep) {
            float kw = (lane < dg) ? keep[sid] : 0.f;
            for (int d = 1; d < 64; d <<= 1) kw += __shfl_xor(kw, d, 64);
            cnt = kw;
        } else {
            cnt = (float)dg;
        }

        int dgc = dg < 64 ? dg : 64;
        float a0 = 0.f, a1 = 0.f;

#define LOADG(buf, g)                                                                   \
    _Pragma("unroll") for (int j = 0; j < 8; ++j) {                                     \
        int s_ = __builtin_amdgcn_readlane(sid, (g) * 8 + j);                           \
        buf[j] = *reinterpret_cast<const u32*>(Y + (size_t)s_ * 256 + lane * 2);        \
    }

        if (dgc > 0) {
            u32 va[8], vb[8];
            int ng = (dgc + 7) >> 3;
            LOADG(va, 0)
            int g = 0;
            for (; g + 2 < ng; g += 2) {
                LOADG(vb, g + 1)
                accg(va, g * 8, dgc, a0, a1);
                LOADG(va, g + 2)
                accg(vb, (g + 1) * 8, dgc, a0, a1);
            }
            if (g + 1 < ng) {
                LOADG(vb, g + 1)
                accg(va, g * 8, dgc, a0, a1);
                accg(vb, (g + 1) * 8, dgc, a0, a1);
            } else {
                accg(va, g * 8, dgc, a0, a1);
            }
        }
#undef LOADG

        for (int e = 64; e < dg; ++e) {  // astronomically rare: degree > 64
            int s = csr[off + e];
            if (keep) cnt += keep[s];
            u32 v = *reinterpret_cast<const u32*>(Y + (size_t)s * 256 + lane * 2);
            a0 += bfu_lo(v);
            a1 += bfu_hi(v);
        }

        float inv = ki / fmaxf(cnt, 1.0f);
        r0 = fmaxf(a0 * inv + bb.x + bfu_lo(vr), 0.f);
        r1 = fmaxf(a1 * inv + bb.y + bfu_hi(vr), 0.f);

        if (outb) {
            u32 p = ((u32)fbf(r1) << 16) | (u32)fbf(r0);
            *reinterpret_cast<u32*>(outb + (size_t)node * 128 + lane * 2) = p;
        }

        if (srel) {  // SAGPool score partial dots (conv2 only)
            float2 w0 = reinterpret_cast<const float2*>(wsrel)[lane];
            float2 w1 = reinterpret_cast<const float2*>(wsroot)[lane];
            float pr = r0 * w0.x + r1 * w0.y;
            float po = r0 * w1.x + r1 * w1.y;
            for (int d = 1; d < 64; d <<= 1) {
                pr += __shfl_xor(pr, d, 64);
                po += __shfl_xor(po, d, 64);
            }
            if (lane == 0) { srel[node] = pr; sroot[node] = po; }
        }
    }

    // pool: LDS partial across the block's 4 nodes, one atomic per feature into
    // this block's bucket (16 buckets per graph)
    pool[wid][lane * 2] = r0;
    pool[wid][lane * 2 + 1] = r1;
    __syncthreads();
    int t = threadIdx.x;
    if (t < 128) {
        float s = pool[0][t] + pool[1][t] + pool[2][t] + pool[3][t];
        int g = blk >> 8;              // 256 blocks per graph (after swizzle)
        int bucket = blk & 15;
        atomicAdd(&xsp[(g * 16 + bucket) * 384 + base + t], s * invdenom);
    }
}

__global__ void score_agg_kernel(const float* __restrict__ srel, const float* __restrict__ sroot,
                                 const float* __restrict__ bs, const int* __restrict__ csr,
                                 const int* __restrict__ noff, const int* __restrict__ deg,
                                 float* __restrict__ score) {
    int i = blockIdx.x * 256 + threadIdx.x;
    if (i >= NN) return;
    int off = noff[i], dg = deg[i];
    float s = 0.f;
    for (int e = 0; e < dg; ++e) s += srel[csr[off + e]];
    score[i] = s / fmaxf((float)dg, 1.0f) + bs[0] + sroot[i];
}

// ---------------- per-graph top-K via bitonic sort (desc score, asc idx tiebreak)
__global__ __launch_bounds__(1024) void topk_kernel(const float* __restrict__ score,
                                                    float* __restrict__ keep,
                                                    float* __restrict__ gate) {
    __shared__ float sc[NPGC];
    __shared__ int si[NPGC];
    int g = blockIdx.x, t = threadIdx.x;
    sc[t] = score[g * NPGC + t];
    si[t] = t;
    __syncthreads();
    for (int k = 2; k <= NPGC; k <<= 1) {
        for (int j = k >> 1; j > 0; j >>= 1) {
            int ixj = t ^ j;
            if (ixj > t) {
                float a = sc[t], b = sc[ixj];
                int ai = si[t], bi = si[ixj];
                bool less = (a > b) || (a == b && ai < bi);
                bool up = ((t & k) == 0);
                if (less != up) { sc[t] = b; sc[ixj] = a; si[t] = bi; si[ixj] = ai; }
            }
            __syncthreads();
        }
    }
    int node = g * NPGC + si[t];
    float kf = (t < KKEEP) ? 1.f : 0.f;
    keep[node] = kf;
    gate[node] = kf * tanhf(sc[t]);
}

// ---------------- MLP head + log_softmax; one block of 512 per graph.
// k-split the 384-wide dot across 4 thread-groups (coalesced Wl1 reads, deep
// load pipeline); layer-2 via LDS-staged Wl2 + wave shfl reduction (no serial
// 10-lane global-load loop).
__global__ __launch_bounds__(512) void mlp_kernel(const float* __restrict__ xsp,
                                                  const float* __restrict__ Wl1,
                                                  const float* __restrict__ bl1,
                                                  const float* __restrict__ Wl2,
                                                  const float* __restrict__ bl2,
                                                  float* __restrict__ out) {
    __shared__ float xsl[384];
    __shared__ float part[4][128];
    __shared__ float wl2s[1280];
    __shared__ float wred[2][10];
    __shared__ float lgs[10];
    int g = blockIdx.x, tid = threadIdx.x;
    int t = tid & 127, kg = tid >> 7;

    for (int i = tid; i < 1280; i += 512) wl2s[i] = Wl2[i];
    if (tid < 384) {
        float s = 0.f;
#pragma unroll
        for (int b = 0; b < 16; ++b) s += xsp[(g * 16 + b) * 384 + tid];
        xsl[tid] = s;
    }
    __syncthreads();

    // partial dot over this group's 96 k values (Wl1 reads coalesced across t)
    float p = 0.f;
    int k0 = kg * 96;
#pragma unroll 8
    for (int k = 0; k < 96; ++k) p += xsl[k0 + k] * Wl1[(k0 + k) * 128 + t];
    part[kg][t] = p;
    __syncthreads();

    if (tid < 128) {
        float h = fmaxf(bl1[t] + part[0][t] + part[1][t] + part[2][t] + part[3][t], 0.f);
        float pc[10];
#pragma unroll
        for (int c = 0; c < 10; ++c) pc[c] = h * wl2s[t * 10 + c];
#pragma unroll
        for (int d = 1; d < 64; d <<= 1) {
#pragma unroll
            for (int c = 0; c < 10; ++c) pc[c] += __shfl_xor(pc[c], d, 64);
        }
        if ((t & 63) == 0) {
#pragma unroll
            for (int c = 0; c < 10; ++c) wred[t >> 6][c] = pc[c];
        }
    }
    __syncthreads();
    if (tid < 10) lgs[tid] = wred[0][tid] + wred[1][tid] + bl2[tid];
    __syncthreads();
    if (tid < 10) {
        float m = lgs[0];
#pragma unroll
        for (int c = 1; c < 10; ++c) m = fmaxf(m, lgs[c]);
        float s = 0.f;
#pragma unroll
        for (int c = 0; c < 10; ++c) s += expf(lgs[c] - m);
        out[g * 10 + tid] = lgs[tid] - m - logf(s);
    }
}

extern "C" void kernel_launch(void* const* d_in, const int* in_sizes, int n_in,
                              void* d_out, int out_size, void* d_ws, size_t ws_size,
                              hipStream_t stream) {
    const float* x       = (const float*)d_in[0];
    const int*   src     = (const int*)d_in[1];
    const int*   dst     = (const int*)d_in[2];
    const float* W1_rel  = (const float*)d_in[3];
    const float* b1      = (const float*)d_in[4];
    const float* W1_root = (const float*)d_in[5];
    const float* W2_rel  = (const float*)d_in[6];
    const float* b2      = (const float*)d_in[7];
    const float* W2_root = (const float*)d_in[8];
    const float* W3_rel  = (const float*)d_in[9];
    const float* b3      = (const float*)d_in[10];
    const float* W3_root = (const float*)d_in[11];
    const float* Ws_rel  = (const float*)d_in[12];
    const float* bs      = (const float*)d_in[13];
    const float* Ws_root = (const float*)d_in[14];
    const float* Wl1     = (const float*)d_in[15];
    const float* bl1     = (const float*)d_in[16];
    const float* Wl2     = (const float*)d_in[17];
    const float* bl2     = (const float*)d_in[18];

    char* ws = (char*)d_ws;
    size_t off = 0;
    auto alloc = [&](size_t bytes) -> void* {
        void* p = ws + off;
        off += (bytes + 255) & ~(size_t)255;
        return p;
    };
    u16*   XB    = (u16*)alloc((size_t)NN * 128 * 2);   // gemm input
    u16*   X2B   = (u16*)alloc((size_t)NN * 128 * 2);   // conv2 output (pre-gate)
    u16*   YB    = (u16*)alloc((size_t)NN * 256 * 2);   // gemm output
    u16*   WT    = (u16*)alloc(3 * 256 * 128 * 2);      // 3 weight sets
    float* SREL  = (float*)alloc(NN * 4);
    float* SROOT = (float*)alloc(NN * 4);
    float* SCORE = (float*)alloc(NN * 4);
    float* GATE  = (float*)alloc(NN * 4);
    float* KEEP  = (float*)alloc(NN * 4);
    int*   DEG   = (int*)alloc(NN * 4);
    int*   NOFF  = (int*)alloc(NN * 4);
    int*   CUR   = (int*)alloc(NN * 4);
    int*   CSR   = (int*)alloc((size_t)EE * 4);
    float* XSP   = (float*)alloc((size_t)BG * 16 * 384 * 4);  // bucketed pool partials
    (void)ws_size; (void)n_in; (void)in_sizes; (void)out_size;

    hipMemsetAsync(DEG, 0, NN * 4, stream);
    hipMemsetAsync(XSP, 0, (size_t)BG * 16 * 384 * 4, stream);

    // CSR build (by dst)
    deg_count_kernel<<<EE / 256, 256, 0, stream>>>(dst, DEG, EE);
    csr_offsets_kernel<<<BG, 256, 0, stream>>>(DEG, NOFF, CUR);
    csr_fill_kernel<<<EE / 256, 256, 0, stream>>>(src, dst, CUR, CSR, EE);

    // cast input to bf16 + prep all 3 weight sets
    cast_kernel<<<(NN * 128 / 4) / 256, 256, 0, stream>>>(x, XB, NN * 128 / 4);
    prep_w_kernel<<<dim3(128, 3), 256, 0, stream>>>(W1_rel, W1_root, W2_rel, W2_root,
                                                    W3_rel, W3_root, WT);

    // ---- conv1 ----
    gemm_kernel<<<dim3(NN / 128, 2), 256, 0, stream>>>(XB, WT, YB);
    agg_kernel<<<NN / 4, 256, 0, stream>>>(YB, CSR, NOFF, DEG, b1, nullptr, XB,
                                           nullptr, nullptr, nullptr, nullptr,
                                           XSP, 0, 1.f / 1024.f);

    // ---- conv2 (+ fused score dots) ----
    gemm_kernel<<<dim3(NN / 128, 2), 256, 0, stream>>>(XB, WT + 32768, YB);
    agg_kernel<<<NN / 4, 256, 0, stream>>>(YB, CSR, NOFF, DEG, b2, nullptr, X2B,
                                           Ws_rel, Ws_root, SREL, SROOT,
                                           XSP, 128, 1.f / 1024.f);

    // ---- SAGPooling ----
    score_agg_kernel<<<NN / 256, 256, 0, stream>>>(SREL, SROOT, bs, CSR, NOFF, DEG, SCORE);
    topk_kernel<<<BG, 1024, 0, stream>>>(SCORE, KEEP, GATE);
    gate_bf16_kernel<<<(NN * 128 / 4) / 256, 256, 0, stream>>>(X2B, GATE, XB, NN * 128 / 4);

    // ---- conv3 (masked) ----
    gemm_kernel<<<dim3(NN / 128, 2), 256, 0, stream>>>(XB, WT + 65536, YB);
    agg_kernel<<<NN / 4, 256, 0, stream>>>(YB, CSR, NOFF, DEG, b3, KEEP, nullptr,
                                           nullptr, nullptr, nullptr, nullptr,
                                           XSP, 256, 1.f / (float)KKEEP);

    // ---- MLP head ----
    mlp_kernel<<<BG, 512, 0, stream>>>(XSP, Wl1, bl1, Wl2, bl2, (float*)d_out);
}